// Round 2
// baseline (216.031 us; speedup 1.0000x reference)
//
#include <hip/hip_runtime.h>
#include <hip/hip_bf16.h>

#define B_SZ   2
#define C_CH   64
#define NQ     8          // q/k channels (C/8)
#define NPIX   9216       // 96*96
#define NJC    288        // NPIX/32 key 32-chunks per batch
#define QBLKS  288        // NPIX/32 query blocks (32 queries per block)
#define KPART  4          // key partitions, one per wave in a block
#define KEYS_P 2304       // NPIX/KPART
#define NCHUNK 36         // 64 keys per chunk
#define PT_W   36         // dwords per P row (32 data + 4 pad; 144B stride)
#define PT_HALF (16*PT_W) // one q-tile P buffer: 576 dwords
#define SM_F   2080       // per-partition combine floats: 2048 O + 32 L
#define NP4    2304       // NPIX/4

typedef short bf16x8 __attribute__((ext_vector_type(8)));
typedef float f32x4  __attribute__((ext_vector_type(4)));

static __device__ __forceinline__ unsigned pack2bf(float a, float b){
    union { __hip_bfloat16 h; unsigned short us; } ca, cb;
    ca.h = __float2bfloat16(a); cb.h = __float2bfloat16(b);
    return (unsigned)ca.us | ((unsigned)cb.us << 16);
}

static __device__ __forceinline__ unsigned short bf16b(float a){
    union { __hip_bfloat16 h; unsigned short us; } c;
    c.h = __float2bfloat16(a); return c.us;
}

// ---------- fused prep, 8-channel register blocking ----------
// blocks [0,144):    proj_v  thread = (b, c8, n4): 4 px, 8 channels
// blocks [144,180):  proj_qk thread = (b, o8, n4): 4 px, all 8 q or k outputs
// blocks [180,308):  GAP
__global__ __launch_bounds__(256) void prep_kernel(
    const float* __restrict__ x,
    const float* __restrict__ wq, const float* __restrict__ bq,
    const float* __restrict__ wk, const float* __restrict__ bk,
    const float* __restrict__ wv, const float* __restrict__ bv,
    __hip_bfloat16* __restrict__ qp, __hip_bfloat16* __restrict__ kp,
    __hip_bfloat16* __restrict__ vswz, float* __restrict__ amean)
{
    const int blk = blockIdx.x, tid = threadIdx.x;
    if (blk < 144){
        int t  = blk*256 + tid;            // (b, c8, n4)
        int n  = (t % NP4) * 4;
        int c8 = (t / NP4) & 7;            // wave-uniform (NP4 % 64 == 0)
        int b  = t / (NP4*8);
        c8 = __builtin_amdgcn_readfirstlane(c8);
        b  = __builtin_amdgcn_readfirstlane(b);
        float acc[8][4];
#pragma unroll
        for (int k = 0; k < 8; ++k){
            float bvv = bv[c8*8 + k];
            acc[k][0] = bvv; acc[k][1] = bvv; acc[k][2] = bvv; acc[k][3] = bvv;
        }
#pragma unroll 4
        for (int ci = 0; ci < C_CH; ++ci){
            const float4 xv = *reinterpret_cast<const float4*>(
                x + (size_t)(b*C_CH + ci)*NPIX + n);
#pragma unroll
            for (int k = 0; k < 8; ++k){
                float w = wv[(c8*8 + k)*C_CH + ci];
                acc[k][0] = fmaf(xv.x, w, acc[k][0]);
                acc[k][1] = fmaf(xv.y, w, acc[k][1]);
                acc[k][2] = fmaf(xv.z, w, acc[k][2]);
                acc[k][3] = fmaf(xv.w, w, acc[k][3]);
            }
        }
#pragma unroll
        for (int k = 0; k < 8; ++k){
            int c = c8*8 + k;
            size_t base = ((size_t)((b*NJC + (n >> 5))*4 + (c >> 4)))*512
                        + ((c & 15)*32) + (n & 31);
            unsigned long long wpk =
                (unsigned long long)pack2bf(acc[k][0], acc[k][1]) |
                ((unsigned long long)pack2bf(acc[k][2], acc[k][3]) << 32);
            *reinterpret_cast<unsigned long long*>(vswz + base) = wpk;
        }
    } else if (blk < 180){
        int t  = (blk - 144)*256 + tid;    // (b, o8, n4)
        int n  = (t % NP4) * 4;
        int o8 = (t / NP4) & 1;            // wave-uniform; 0 => q, 1 => k
        int b  = t / (NP4*2);
        o8 = __builtin_amdgcn_readfirstlane(o8);
        b  = __builtin_amdgcn_readfirstlane(b);
        const bool isq = (o8 == 0);
        const float* w    = isq ? wq : wk;
        const float* bias = isq ? bq : bk;
        float acc[8][4];
#pragma unroll
        for (int k = 0; k < 8; ++k){
            float bb = bias[k];
            acc[k][0] = bb; acc[k][1] = bb; acc[k][2] = bb; acc[k][3] = bb;
        }
#pragma unroll 4
        for (int ci = 0; ci < C_CH; ++ci){
            const float4 xv = *reinterpret_cast<const float4*>(
                x + (size_t)(b*C_CH + ci)*NPIX + n);
#pragma unroll
            for (int k = 0; k < 8; ++k){
                float wv_ = w[k*C_CH + ci];
                acc[k][0] = fmaf(xv.x, wv_, acc[k][0]);
                acc[k][1] = fmaf(xv.y, wv_, acc[k][1]);
                acc[k][2] = fmaf(xv.z, wv_, acc[k][2]);
                acc[k][3] = fmaf(xv.w, wv_, acc[k][3]);
            }
        }
        if (isq){  // fold log2(e) so softmax uses native exp2
#pragma unroll
            for (int k = 0; k < 8; ++k)
#pragma unroll
                for (int px = 0; px < 4; ++px) acc[k][px] *= 1.44269504f;
        }
        __hip_bfloat16* dst = isq ? qp : kp;
#pragma unroll
        for (int px = 0; px < 4; ++px){
            bf16x8 row;
#pragma unroll
            for (int k = 0; k < 8; ++k) row[k] = (short)bf16b(acc[k][px]);
            *reinterpret_cast<bf16x8*>(dst + ((size_t)(b*NPIX + n + px))*NQ) = row;
        }
    } else {
        int bc = blk - 180;                // (b*64+c)
        float s = 0.f;
        for (int i = tid; i < NPIX; i += 256) s += x[(size_t)bc*NPIX + i];
#pragma unroll
        for (int o = 32; o > 0; o >>= 1) s += __shfl_down(s, o, 64);
        __shared__ float red[4];
        if ((tid & 63) == 0) red[tid >> 6] = s;
        __syncthreads();
        if (tid == 0) amean[bc] = (red[0] + red[1] + red[2] + red[3]) * (1.f / (float)NPIX);
    }
}

// ---------- fused attention (32 queries/block) + SE + combine + epilogue ----------
__global__ __launch_bounds__(256, 4) void flash_fused(
    const __hip_bfloat16* __restrict__ qp,
    const __hip_bfloat16* __restrict__ kp,
    const __hip_bfloat16* __restrict__ vswz,
    const float* __restrict__ amean,
    const float* __restrict__ sw1, const float* __restrict__ sb1,
    const float* __restrict__ s1w, const float* __restrict__ s1b,
    const float* __restrict__ s1m, const float* __restrict__ s1v,
    const float* __restrict__ sw2, const float* __restrict__ sb2,
    const float* __restrict__ s2w, const float* __restrict__ s2b,
    const float* __restrict__ s2m, const float* __restrict__ s2v,
    const float* __restrict__ x,
    const float* __restrict__ gamma,
    const float* __restrict__ bnw, const float* __restrict__ bnb,
    const float* __restrict__ bnm, const float* __restrict__ bnv,
    float* __restrict__ out)
{
    __shared__ __align__(16) unsigned lds[KPART*4*PT_HALF];   // 36864 B: P bufs / combine overlay

    const int qt2 = blockIdx.x, b = blockIdx.y;   // 32 queries per block
    const int p  = threadIdx.x >> 6;     // wave = key partition
    const int l  = threadIdx.x & 63;
    const int lq = l & 15;               // query column
    const int lg = l >> 4;               // lane group
    unsigned* pt = lds + p*(4*PT_HALF);  // this wave's 2-parity x 2-qtile P buffers
    const int vlane = lq*32 + lg*8;      // bf16 offset of this lane's V frag in a 1KB tile

    // --- SE a1 (redundant per wave; independent of attention) ---
    float a1r;
    {
        int r8 = l & 7;
        float s = sb1[r8];
#pragma unroll 8
        for (int c = 0; c < C_CH; ++c)
            s = fmaf(amean[b*C_CH + c], sw1[r8*C_CH + c], s);
        s = (s - s1m[r8]) * (s1w[r8] * rsqrtf(s1v[r8] + 1e-5f)) + s1b[r8];
        a1r = fmaxf(s, 0.f);
    }

    bf16x8 zf = {0,0,0,0,0,0,0,0};
    bf16x8 qfrag[2];      // B-operand: B[d = lg*8+j][n = lq] for 2 q-tiles
#pragma unroll
    for (int qi = 0; qi < 2; ++qi){
        qfrag[qi] = zf;
        if (lg == 0)
            qfrag[qi] = *reinterpret_cast<const bf16x8*>(
                qp + (size_t)(b*NPIX + qt2*32 + qi*16 + lq) * NQ);
    }

    bf16x8 ones;          // bf16 1.0 x8 — constant A-frag for the L-denominator MFMA
#pragma unroll
    for (int i = 0; i < 8; ++i) ones[i] = (short)0x3F80;

    f32x4 Of[2][4];
#pragma unroll
    for (int qi = 0; qi < 2; ++qi)
#pragma unroll
        for (int i = 0; i < 4; ++i) Of[qi][i] = (f32x4){0.f, 0.f, 0.f, 0.f};
    f32x4 Lf[2];
    Lf[0] = (f32x4){0.f, 0.f, 0.f, 0.f};
    Lf[1] = (f32x4){0.f, 0.f, 0.f, 0.f};

    for (int ch = 0; ch < NCHUNK; ++ch){
        const int j0  = p*KEYS_P + ch*64;
        const int jcb = b*NJC + (j0 >> 5);          // global 32-key chunk index
        unsigned* ptb0 = pt + (ch & 1)*(2*PT_HALF);

        // --- K fragments (lane-group 0 holds the real K-dim) ---
        bf16x8 kf[4];
#pragma unroll
        for (int jt = 0; jt < 4; ++jt){
            kf[jt] = zf;
            if (lg == 0)
                kf[jt] = *reinterpret_cast<const bf16x8*>(kp + (size_t)(b*NPIX + j0 + jt*16 + lq) * NQ);
        }
        // --- V fragments: contiguous 1KB per (kc,ct) tile; reused for both q-tiles ---
        bf16x8 vf[2][4];
#pragma unroll
        for (int kc = 0; kc < 2; ++kc)
#pragma unroll
            for (int ct = 0; ct < 4; ++ct)
                vf[kc][ct] = *reinterpret_cast<const bf16x8*>(
                    vswz + ((size_t)((jcb + kc)*4 + ct))*512 + vlane);

        // --- S^T = K·Q^T, P = exp2(S), store per q-tile ---
#pragma unroll
        for (int qi = 0; qi < 2; ++qi){
            unsigned* ptb = ptb0 + qi*PT_HALF;
            f32x4 Sf[4];
#pragma unroll
            for (int jt = 0; jt < 4; ++jt)
                Sf[jt] = __builtin_amdgcn_mfma_f32_16x16x32_bf16(kf[jt], qfrag[qi], (f32x4){0.f,0.f,0.f,0.f}, 0, 0, 0);
#pragma unroll
            for (int jt = 0; jt < 4; ++jt){
                unsigned lo = pack2bf(exp2f(Sf[jt][0]), exp2f(Sf[jt][1]));
                unsigned hi = pack2bf(exp2f(Sf[jt][2]), exp2f(Sf[jt][3]));
                *reinterpret_cast<unsigned long long*>(&ptb[lq*PT_W + jt*8 + lg*2]) =
                    (unsigned long long)lo | ((unsigned long long)hi << 32);
            }
        }
        // --- O^T += V^T·P^T ; L += ones·P^T  (V frags reused across q-tiles) ---
#pragma unroll
        for (int kc = 0; kc < 2; ++kc){
#pragma unroll
            for (int qi = 0; qi < 2; ++qi){
                bf16x8 pf = *reinterpret_cast<const bf16x8*>(
                    &ptb0[qi*PT_HALF + lq*PT_W + kc*16 + lg*4]);
#pragma unroll
                for (int ct = 0; ct < 4; ++ct)
                    Of[qi][ct] = __builtin_amdgcn_mfma_f32_16x16x32_bf16(vf[kc][ct], pf, Of[qi][ct], 0, 0, 0);
                Lf[qi] = __builtin_amdgcn_mfma_f32_16x16x32_bf16(ones, pf, Lf[qi], 0, 0, 0);
            }
        }
    }

    // --- stage partials (overlays P buffers: barrier first) ---
    __syncthreads();
    float* sm = reinterpret_cast<float*>(lds);
#pragma unroll
    for (int qi = 0; qi < 2; ++qi)
#pragma unroll
        for (int ct = 0; ct < 4; ++ct)
#pragma unroll
            for (int r = 0; r < 4; ++r)
                sm[p*SM_F + qi*1024 + (ct*4 + r)*64 + l] = Of[qi][ct][r];
    if (l < 16){
        sm[p*SM_F + 2048 + lq]      = Lf[0][0];
        sm[p*SM_F + 2048 + 16 + lq] = Lf[1][0];
    }
    __syncthreads();

    // --- combine partitions + SE a2 + epilogue: out = x*(1+a2) + BN(gamma*O/L) ---
    {
        const int ct = threadIdx.x >> 6;   // each thread: 4 channels x 1 pixel x 2 q-tiles
        float gam = gamma[0];

        // SE a2 for this thread's 4 channels (gather a1 via shuffles)
        float a1g[8];
#pragma unroll
        for (int j = 0; j < 8; ++j) a1g[j] = __shfl(a1r, (l & 56) | j, 64);
        float a2v[4];
#pragma unroll
        for (int r = 0; r < 4; ++r){
            int c = ct*16 + lg*4 + r;
            float s = sb2[c];
#pragma unroll
            for (int j = 0; j < 8; ++j) s = fmaf(a1g[j], sw2[c*NQ + j], s);
            s = (s - s2m[c]) * (s2w[c] * rsqrtf(s2v[c] + 1e-5f)) + s2b[c];
            a2v[r] = fmaxf(s, 0.f);
        }

#pragma unroll
        for (int qi = 0; qi < 2; ++qi){
            float L = 0.f;
#pragma unroll
            for (int q = 0; q < KPART; ++q) L += sm[q*SM_F + 2048 + qi*16 + lq];
            float invL = 1.f / L;
            int n = qt2*32 + qi*16 + lq;
#pragma unroll
            for (int r = 0; r < 4; ++r){
                float O = 0.f;
#pragma unroll
                for (int q = 0; q < KPART; ++q) O += sm[q*SM_F + qi*1024 + (ct*4 + r)*64 + l];
                int c = ct*16 + lg*4 + r;
                float pam = gam * O * invL;
                pam = (pam - bnm[c]) * (bnw[c] * rsqrtf(bnv[c] + 1e-5f)) + bnb[c];
                float xv = x[(size_t)(b*C_CH + c)*NPIX + n];
                out[(size_t)(b*C_CH + c)*NPIX + n] = fmaf(xv, a2v[r], xv + pam);
            }
        }
    }
}

extern "C" void kernel_launch(void* const* d_in, const int* in_sizes, int n_in,
                              void* d_out, int out_size, void* d_ws, size_t ws_size,
                              hipStream_t stream)
{
    const float* x     = (const float*)d_in[0];
    const float* wq    = (const float*)d_in[1];
    const float* bq    = (const float*)d_in[2];
    const float* wk    = (const float*)d_in[3];
    const float* bk    = (const float*)d_in[4];
    const float* wv    = (const float*)d_in[5];
    const float* bv    = (const float*)d_in[6];
    const float* gamma = (const float*)d_in[7];
    const float* bnw   = (const float*)d_in[8];
    const float* bnb   = (const float*)d_in[9];
    const float* bnm   = (const float*)d_in[10];
    const float* bnv   = (const float*)d_in[11];
    const float* sw1   = (const float*)d_in[12];
    const float* sb1   = (const float*)d_in[13];
    const float* s1w   = (const float*)d_in[14];
    const float* s1b   = (const float*)d_in[15];
    const float* s1m   = (const float*)d_in[16];
    const float* s1v   = (const float*)d_in[17];
    const float* sw2   = (const float*)d_in[18];
    const float* sb2   = (const float*)d_in[19];
    const float* s2w   = (const float*)d_in[20];
    const float* s2b   = (const float*)d_in[21];
    const float* s2m   = (const float*)d_in[22];
    const float* s2v   = (const float*)d_in[23];

    size_t off = 0;
    auto give = [&](size_t bytes) -> void* {
        void* r = (char*)d_ws + off;
        off += (bytes + 255) & ~(size_t)255;
        return r;
    };
    __hip_bfloat16* qp   = (__hip_bfloat16*)give((size_t)B_SZ*NPIX*NQ*2);
    __hip_bfloat16* kp   = (__hip_bfloat16*)give((size_t)B_SZ*NPIX*NQ*2);
    __hip_bfloat16* vswz = (__hip_bfloat16*)give((size_t)B_SZ*C_CH*NPIX*2);
    float* amean = (float*)give((size_t)B_SZ*C_CH*4);

    prep_kernel<<<dim3(308), dim3(256), 0, stream>>>(x, wq, bq, wk, bk, wv, bv,
                                                     qp, kp, vswz, amean);
    flash_fused<<<dim3(QBLKS, B_SZ), dim3(256), 0, stream>>>(
        qp, kp, vswz, amean,
        sw1, sb1, s1w, s1b, s1m, s1v,
        sw2, sb2, s2w, s2b, s2m, s2v,
        x, gamma, bnw, bnb, bnm, bnv, (float*)d_out);
}

// Round 3
// 212.856 us; speedup vs baseline: 1.0149x; 1.0149x over previous
//
#include <hip/hip_runtime.h>
#include <hip/hip_bf16.h>

#define B_SZ   2
#define C_CH   64
#define NQ     8          // q/k channels (C/8)
#define NPIX   9216       // 96*96
#define NJC    288        // NPIX/32 key 32-chunks per batch
#define QBLKS  288        // NPIX/32 query blocks (32 queries per block)
#define KPART  4          // key partitions, one per wave in a block
#define KEYS_P 2304       // NPIX/KPART
#define NCHUNK 36         // 64 keys per chunk
#define SM_F   2080       // per-partition combine floats: 2048 O + 32 L
#define NP4    2304       // NPIX/4

typedef short bf16x8 __attribute__((ext_vector_type(8)));
typedef float f32x4  __attribute__((ext_vector_type(4)));
typedef unsigned u32x4 __attribute__((ext_vector_type(4)));
typedef unsigned uint2v __attribute__((ext_vector_type(2)));

static __device__ __forceinline__ unsigned pack2bf(float a, float b){
    union { __hip_bfloat16 h; unsigned short us; } ca, cb;
    ca.h = __float2bfloat16(a); cb.h = __float2bfloat16(b);
    return (unsigned)ca.us | ((unsigned)cb.us << 16);
}

static __device__ __forceinline__ unsigned short bf16b(float a){
    union { __hip_bfloat16 h; unsigned short us; } c;
    c.h = __float2bfloat16(a); return c.us;
}

// ---------- fused prep, 8-channel register blocking (unchanged) ----------
__global__ __launch_bounds__(256) void prep_kernel(
    const float* __restrict__ x,
    const float* __restrict__ wq, const float* __restrict__ bq,
    const float* __restrict__ wk, const float* __restrict__ bk,
    const float* __restrict__ wv, const float* __restrict__ bv,
    __hip_bfloat16* __restrict__ qp, __hip_bfloat16* __restrict__ kp,
    __hip_bfloat16* __restrict__ vswz, float* __restrict__ amean)
{
    const int blk = blockIdx.x, tid = threadIdx.x;
    if (blk < 144){
        int t  = blk*256 + tid;            // (b, c8, n4)
        int n  = (t % NP4) * 4;
        int c8 = (t / NP4) & 7;            // wave-uniform (NP4 % 64 == 0)
        int b  = t / (NP4*8);
        c8 = __builtin_amdgcn_readfirstlane(c8);
        b  = __builtin_amdgcn_readfirstlane(b);
        float acc[8][4];
#pragma unroll
        for (int k = 0; k < 8; ++k){
            float bvv = bv[c8*8 + k];
            acc[k][0] = bvv; acc[k][1] = bvv; acc[k][2] = bvv; acc[k][3] = bvv;
        }
#pragma unroll 4
        for (int ci = 0; ci < C_CH; ++ci){
            const float4 xv = *reinterpret_cast<const float4*>(
                x + (size_t)(b*C_CH + ci)*NPIX + n);
#pragma unroll
            for (int k = 0; k < 8; ++k){
                float w = wv[(c8*8 + k)*C_CH + ci];
                acc[k][0] = fmaf(xv.x, w, acc[k][0]);
                acc[k][1] = fmaf(xv.y, w, acc[k][1]);
                acc[k][2] = fmaf(xv.z, w, acc[k][2]);
                acc[k][3] = fmaf(xv.w, w, acc[k][3]);
            }
        }
#pragma unroll
        for (int k = 0; k < 8; ++k){
            int c = c8*8 + k;
            size_t base = ((size_t)((b*NJC + (n >> 5))*4 + (c >> 4)))*512
                        + ((c & 15)*32) + (n & 31);
            unsigned long long wpk =
                (unsigned long long)pack2bf(acc[k][0], acc[k][1]) |
                ((unsigned long long)pack2bf(acc[k][2], acc[k][3]) << 32);
            *reinterpret_cast<unsigned long long*>(vswz + base) = wpk;
        }
    } else if (blk < 180){
        int t  = (blk - 144)*256 + tid;    // (b, o8, n4)
        int n  = (t % NP4) * 4;
        int o8 = (t / NP4) & 1;            // wave-uniform; 0 => q, 1 => k
        int b  = t / (NP4*2);
        o8 = __builtin_amdgcn_readfirstlane(o8);
        b  = __builtin_amdgcn_readfirstlane(b);
        const bool isq = (o8 == 0);
        const float* w    = isq ? wq : wk;
        const float* bias = isq ? bq : bk;
        float acc[8][4];
#pragma unroll
        for (int k = 0; k < 8; ++k){
            float bb = bias[k];
            acc[k][0] = bb; acc[k][1] = bb; acc[k][2] = bb; acc[k][3] = bb;
        }
#pragma unroll 4
        for (int ci = 0; ci < C_CH; ++ci){
            const float4 xv = *reinterpret_cast<const float4*>(
                x + (size_t)(b*C_CH + ci)*NPIX + n);
#pragma unroll
            for (int k = 0; k < 8; ++k){
                float wv_ = w[k*C_CH + ci];
                acc[k][0] = fmaf(xv.x, wv_, acc[k][0]);
                acc[k][1] = fmaf(xv.y, wv_, acc[k][1]);
                acc[k][2] = fmaf(xv.z, wv_, acc[k][2]);
                acc[k][3] = fmaf(xv.w, wv_, acc[k][3]);
            }
        }
        if (isq){  // fold log2(e) so softmax uses native exp2
#pragma unroll
            for (int k = 0; k < 8; ++k)
#pragma unroll
                for (int px = 0; px < 4; ++px) acc[k][px] *= 1.44269504f;
        }
        __hip_bfloat16* dst = isq ? qp : kp;
#pragma unroll
        for (int px = 0; px < 4; ++px){
            bf16x8 row;
#pragma unroll
            for (int k = 0; k < 8; ++k) row[k] = (short)bf16b(acc[k][px]);
            *reinterpret_cast<bf16x8*>(dst + ((size_t)(b*NPIX + n + px))*NQ) = row;
        }
    } else {
        int bc = blk - 180;                // (b*64+c)
        float s = 0.f;
        for (int i = tid; i < NPIX; i += 256) s += x[(size_t)bc*NPIX + i];
#pragma unroll
        for (int o = 32; o > 0; o >>= 1) s += __shfl_down(s, o, 64);
        __shared__ float red[4];
        if ((tid & 63) == 0) red[tid >> 6] = s;
        __syncthreads();
        if (tid == 0) amean[bc] = (red[0] + red[1] + red[2] + red[3]) * (1.f / (float)NPIX);
    }
}

// ---------- fused attention (32 q/block) + SE + combine; P exchange via permlane ----------
__global__ __launch_bounds__(256, 4) void flash_fused(
    const __hip_bfloat16* __restrict__ qp,
    const __hip_bfloat16* __restrict__ kp,
    const __hip_bfloat16* __restrict__ vswz,
    const float* __restrict__ amean,
    const float* __restrict__ sw1, const float* __restrict__ sb1,
    const float* __restrict__ s1w, const float* __restrict__ s1b,
    const float* __restrict__ s1m, const float* __restrict__ s1v,
    const float* __restrict__ sw2, const float* __restrict__ sb2,
    const float* __restrict__ s2w, const float* __restrict__ s2b,
    const float* __restrict__ s2m, const float* __restrict__ s2v,
    const float* __restrict__ x,
    const float* __restrict__ gamma,
    const float* __restrict__ bnw, const float* __restrict__ bnb,
    const float* __restrict__ bnm, const float* __restrict__ bnv,
    float* __restrict__ out)
{
    __shared__ __align__(16) float sm[KPART*SM_F];   // 33280 B: combine partials only

    const int qt2 = blockIdx.x, b = blockIdx.y;   // 32 queries per block
    const int p  = threadIdx.x >> 6;     // wave = key partition
    const int l  = threadIdx.x & 63;
    const int lq = l & 15;               // query column
    const int lg = l >> 4;               // lane group
    const int vlane = lq*32 + lg*8;      // bf16 offset of this lane's V frag in a 1KB tile

    // --- SE a1 (redundant per wave; independent of attention) ---
    float a1r;
    {
        int r8 = l & 7;
        float s = sb1[r8];
#pragma unroll 8
        for (int c = 0; c < C_CH; ++c)
            s = fmaf(amean[b*C_CH + c], sw1[r8*C_CH + c], s);
        s = (s - s1m[r8]) * (s1w[r8] * rsqrtf(s1v[r8] + 1e-5f)) + s1b[r8];
        a1r = fmaxf(s, 0.f);
    }

    bf16x8 zf = {0,0,0,0,0,0,0,0};
    bf16x8 qfrag[2];      // B-operand: B[d = lg*8+j][n = lq] for 2 q-tiles
#pragma unroll
    for (int qi = 0; qi < 2; ++qi){
        qfrag[qi] = zf;
        if (lg == 0)
            qfrag[qi] = *reinterpret_cast<const bf16x8*>(
                qp + (size_t)(b*NPIX + qt2*32 + qi*16 + lq) * NQ);
    }

    bf16x8 ones;          // bf16 1.0 x8 — constant A-frag for the L-denominator MFMA
#pragma unroll
    for (int i = 0; i < 8; ++i) ones[i] = (short)0x3F80;

    f32x4 Of[2][4];
#pragma unroll
    for (int qi = 0; qi < 2; ++qi)
#pragma unroll
        for (int i = 0; i < 4; ++i) Of[qi][i] = (f32x4){0.f, 0.f, 0.f, 0.f};
    f32x4 Lf[2];
    Lf[0] = (f32x4){0.f, 0.f, 0.f, 0.f};
    Lf[1] = (f32x4){0.f, 0.f, 0.f, 0.f};

    for (int ch = 0; ch < NCHUNK; ++ch){
        const int j0  = p*KEYS_P + ch*64;
        const int jcb = b*NJC + (j0 >> 5);          // global 32-key chunk index

        // --- K fragments (lane-group 0 holds the real K-dim) ---
        bf16x8 kf[4];
#pragma unroll
        for (int jt = 0; jt < 4; ++jt){
            kf[jt] = zf;
            if (lg == 0)
                kf[jt] = *reinterpret_cast<const bf16x8*>(kp + (size_t)(b*NPIX + j0 + jt*16 + lq) * NQ);
        }
        // --- V fragments: contiguous 1KB per (kc,ct) tile; reused for both q-tiles ---
        bf16x8 vf[2][4];
#pragma unroll
        for (int kc = 0; kc < 2; ++kc)
#pragma unroll
            for (int ct = 0; ct < 4; ++ct)
                vf[kc][ct] = *reinterpret_cast<const bf16x8*>(
                    vswz + ((size_t)((jcb + kc)*4 + ct))*512 + vlane);

#pragma unroll
        for (int qi = 0; qi < 2; ++qi){
            // --- S^T = K·Q^T : Sf[jt][r] = S[key j0+jt*16+lg*4+r][query lq] ---
            f32x4 Sf[4];
#pragma unroll
            for (int jt = 0; jt < 4; ++jt)
                Sf[jt] = __builtin_amdgcn_mfma_f32_16x16x32_bf16(kf[jt], qfrag[qi], (f32x4){0.f,0.f,0.f,0.f}, 0, 0, 0);

            // --- P = exp2(S); pack key-pairs: D[jt][i] holds pair-id jt*8+lg*2+i ---
            unsigned D[4][2];
#pragma unroll
            for (int jt = 0; jt < 4; ++jt){
                D[jt][0] = pack2bf(exp2f(Sf[jt][0]), exp2f(Sf[jt][1]));
                D[jt][1] = pack2bf(exp2f(Sf[jt][2]), exp2f(Sf[jt][3]));
            }

            // --- in-register P redistribution: lane-group lg must hold pair-ids
            //     kc*16+lg*4+d in dword d.  permlane32_swap (d.h1<->s.h0) then
            //     permlane16_swap (d.q1<->s.q0, d.q3<->s.q2) yields exactly the
            //     even/odd target dwords. Replaces the LDS P round-trip. ---
#pragma unroll
            for (int kc = 0; kc < 2; ++kc){
                unsigned o0, o1, o2, o3;
                {
                    uint2v r1 = __builtin_amdgcn_permlane32_swap(D[2*kc][0], D[2*kc+1][0], false, false);
                    uint2v r2 = __builtin_amdgcn_permlane16_swap(r1[0], r1[1], false, false);
                    o0 = r2[0]; o2 = r2[1];
                }
                {
                    uint2v r1 = __builtin_amdgcn_permlane32_swap(D[2*kc][1], D[2*kc+1][1], false, false);
                    uint2v r2 = __builtin_amdgcn_permlane16_swap(r1[0], r1[1], false, false);
                    o1 = r2[0]; o3 = r2[1];
                }
                u32x4 pu; pu[0] = o0; pu[1] = o1; pu[2] = o2; pu[3] = o3;
                bf16x8 pf = __builtin_bit_cast(bf16x8, pu);
#pragma unroll
                for (int ct = 0; ct < 4; ++ct)
                    Of[qi][ct] = __builtin_amdgcn_mfma_f32_16x16x32_bf16(vf[kc][ct], pf, Of[qi][ct], 0, 0, 0);
                Lf[qi] = __builtin_amdgcn_mfma_f32_16x16x32_bf16(ones, pf, Lf[qi], 0, 0, 0);
            }
        }
    }

    // --- stage partials (disjoint per-wave regions; one barrier before cross-read) ---
#pragma unroll
    for (int qi = 0; qi < 2; ++qi)
#pragma unroll
        for (int ct = 0; ct < 4; ++ct)
#pragma unroll
            for (int r = 0; r < 4; ++r)
                sm[p*SM_F + qi*1024 + (ct*4 + r)*64 + l] = Of[qi][ct][r];
    if (l < 16){
        sm[p*SM_F + 2048 + lq]      = Lf[0][0];
        sm[p*SM_F + 2048 + 16 + lq] = Lf[1][0];
    }
    __syncthreads();

    // --- combine partitions + SE a2 + epilogue: out = x*(1+a2) + BN(gamma*O/L) ---
    {
        const int ct = threadIdx.x >> 6;   // each thread: 4 channels x 1 pixel x 2 q-tiles
        float gam = gamma[0];

        // SE a2 for this thread's 4 channels (gather a1 via shuffles)
        float a1g[8];
#pragma unroll
        for (int j = 0; j < 8; ++j) a1g[j] = __shfl(a1r, (l & 56) | j, 64);
        float a2v[4];
#pragma unroll
        for (int r = 0; r < 4; ++r){
            int c = ct*16 + lg*4 + r;
            float s = sb2[c];
#pragma unroll
            for (int j = 0; j < 8; ++j) s = fmaf(a1g[j], sw2[c*NQ + j], s);
            s = (s - s2m[c]) * (s2w[c] * rsqrtf(s2v[c] + 1e-5f)) + s2b[c];
            a2v[r] = fmaxf(s, 0.f);
        }

#pragma unroll
        for (int qi = 0; qi < 2; ++qi){
            float L = 0.f;
#pragma unroll
            for (int q = 0; q < KPART; ++q) L += sm[q*SM_F + 2048 + qi*16 + lq];
            float invL = 1.f / L;
            int n = qt2*32 + qi*16 + lq;
#pragma unroll
            for (int r = 0; r < 4; ++r){
                float O = 0.f;
#pragma unroll
                for (int q = 0; q < KPART; ++q) O += sm[q*SM_F + qi*1024 + (ct*4 + r)*64 + l];
                int c = ct*16 + lg*4 + r;
                float pam = gam * O * invL;
                pam = (pam - bnm[c]) * (bnw[c] * rsqrtf(bnv[c] + 1e-5f)) + bnb[c];
                float xv = x[(size_t)(b*C_CH + c)*NPIX + n];
                out[(size_t)(b*C_CH + c)*NPIX + n] = fmaf(xv, a2v[r], xv + pam);
            }
        }
    }
}

extern "C" void kernel_launch(void* const* d_in, const int* in_sizes, int n_in,
                              void* d_out, int out_size, void* d_ws, size_t ws_size,
                              hipStream_t stream)
{
    const float* x     = (const float*)d_in[0];
    const float* wq    = (const float*)d_in[1];
    const float* bq    = (const float*)d_in[2];
    const float* wk    = (const float*)d_in[3];
    const float* bk    = (const float*)d_in[4];
    const float* wv    = (const float*)d_in[5];
    const float* bv    = (const float*)d_in[6];
    const float* gamma = (const float*)d_in[7];
    const float* bnw   = (const float*)d_in[8];
    const float* bnb   = (const float*)d_in[9];
    const float* bnm   = (const float*)d_in[10];
    const float* bnv   = (const float*)d_in[11];
    const float* sw1   = (const float*)d_in[12];
    const float* sb1   = (const float*)d_in[13];
    const float* s1w   = (const float*)d_in[14];
    const float* s1b   = (const float*)d_in[15];
    const float* s1m   = (const float*)d_in[16];
    const float* s1v   = (const float*)d_in[17];
    const float* sw2   = (const float*)d_in[18];
    const float* sb2   = (const float*)d_in[19];
    const float* s2w   = (const float*)d_in[20];
    const float* s2b   = (const float*)d_in[21];
    const float* s2m   = (const float*)d_in[22];
    const float* s2v   = (const float*)d_in[23];

    size_t off = 0;
    auto give = [&](size_t bytes) -> void* {
        void* r = (char*)d_ws + off;
        off += (bytes + 255) & ~(size_t)255;
        return r;
    };
    __hip_bfloat16* qp   = (__hip_bfloat16*)give((size_t)B_SZ*NPIX*NQ*2);
    __hip_bfloat16* kp   = (__hip_bfloat16*)give((size_t)B_SZ*NPIX*NQ*2);
    __hip_bfloat16* vswz = (__hip_bfloat16*)give((size_t)B_SZ*C_CH*NPIX*2);
    float* amean = (float*)give((size_t)B_SZ*C_CH*4);

    prep_kernel<<<dim3(308), dim3(256), 0, stream>>>(x, wq, bq, wk, bk, wv, bv,
                                                     qp, kp, vswz, amean);
    flash_fused<<<dim3(QBLKS, B_SZ), dim3(256), 0, stream>>>(
        qp, kp, vswz, amean,
        sw1, sb1, s1w, s1b, s1m, s1v,
        sw2, sb2, s2w, s2b, s2m, s2v,
        x, gamma, bnw, bnb, bnm, bnv, (float*)d_out);
}

// Round 4
// 211.737 us; speedup vs baseline: 1.0203x; 1.0053x over previous
//
#include <hip/hip_runtime.h>
#include <hip/hip_bf16.h>

#define B_SZ   2
#define C_CH   64
#define NQ     8          // q/k channels (C/8)
#define NPIX   9216       // 96*96
#define NJC    288        // NPIX/32 key 32-chunks per batch
#define QBLKS  288        // NPIX/32 query blocks (32 queries per block)
#define KPART  8          // key partitions, one per wave in a block
#define KEYS_P 1152       // NPIX/KPART
#define NCHUNK 18         // 64 keys per chunk
#define SM_F   2080       // per-slot combine floats: 2048 O + 32 L (4 slots, tree-combined)
#define NP4    2304       // NPIX/4

typedef short bf16x8 __attribute__((ext_vector_type(8)));
typedef float f32x4  __attribute__((ext_vector_type(4)));
typedef unsigned u32x4 __attribute__((ext_vector_type(4)));
typedef unsigned uint2v __attribute__((ext_vector_type(2)));

static __device__ __forceinline__ unsigned pack2bf(float a, float b){
    union { __hip_bfloat16 h; unsigned short us; } ca, cb;
    ca.h = __float2bfloat16(a); cb.h = __float2bfloat16(b);
    return (unsigned)ca.us | ((unsigned)cb.us << 16);
}

static __device__ __forceinline__ unsigned short bf16b(float a){
    union { __hip_bfloat16 h; unsigned short us; } c;
    c.h = __float2bfloat16(a); return c.us;
}

// ---------- fused prep, 8-channel register blocking (unchanged) ----------
__global__ __launch_bounds__(256) void prep_kernel(
    const float* __restrict__ x,
    const float* __restrict__ wq, const float* __restrict__ bq,
    const float* __restrict__ wk, const float* __restrict__ bk,
    const float* __restrict__ wv, const float* __restrict__ bv,
    __hip_bfloat16* __restrict__ qp, __hip_bfloat16* __restrict__ kp,
    __hip_bfloat16* __restrict__ vswz, float* __restrict__ amean)
{
    const int blk = blockIdx.x, tid = threadIdx.x;
    if (blk < 144){
        int t  = blk*256 + tid;            // (b, c8, n4)
        int n  = (t % NP4) * 4;
        int c8 = (t / NP4) & 7;            // wave-uniform (NP4 % 64 == 0)
        int b  = t / (NP4*8);
        c8 = __builtin_amdgcn_readfirstlane(c8);
        b  = __builtin_amdgcn_readfirstlane(b);
        float acc[8][4];
#pragma unroll
        for (int k = 0; k < 8; ++k){
            float bvv = bv[c8*8 + k];
            acc[k][0] = bvv; acc[k][1] = bvv; acc[k][2] = bvv; acc[k][3] = bvv;
        }
#pragma unroll 4
        for (int ci = 0; ci < C_CH; ++ci){
            const float4 xv = *reinterpret_cast<const float4*>(
                x + (size_t)(b*C_CH + ci)*NPIX + n);
#pragma unroll
            for (int k = 0; k < 8; ++k){
                float w = wv[(c8*8 + k)*C_CH + ci];
                acc[k][0] = fmaf(xv.x, w, acc[k][0]);
                acc[k][1] = fmaf(xv.y, w, acc[k][1]);
                acc[k][2] = fmaf(xv.z, w, acc[k][2]);
                acc[k][3] = fmaf(xv.w, w, acc[k][3]);
            }
        }
#pragma unroll
        for (int k = 0; k < 8; ++k){
            int c = c8*8 + k;
            size_t base = ((size_t)((b*NJC + (n >> 5))*4 + (c >> 4)))*512
                        + ((c & 15)*32) + (n & 31);
            unsigned long long wpk =
                (unsigned long long)pack2bf(acc[k][0], acc[k][1]) |
                ((unsigned long long)pack2bf(acc[k][2], acc[k][3]) << 32);
            *reinterpret_cast<unsigned long long*>(vswz + base) = wpk;
        }
    } else if (blk < 180){
        int t  = (blk - 144)*256 + tid;    // (b, o8, n4)
        int n  = (t % NP4) * 4;
        int o8 = (t / NP4) & 1;            // wave-uniform; 0 => q, 1 => k
        int b  = t / (NP4*2);
        o8 = __builtin_amdgcn_readfirstlane(o8);
        b  = __builtin_amdgcn_readfirstlane(b);
        const bool isq = (o8 == 0);
        const float* w    = isq ? wq : wk;
        const float* bias = isq ? bq : bk;
        float acc[8][4];
#pragma unroll
        for (int k = 0; k < 8; ++k){
            float bb = bias[k];
            acc[k][0] = bb; acc[k][1] = bb; acc[k][2] = bb; acc[k][3] = bb;
        }
#pragma unroll 4
        for (int ci = 0; ci < C_CH; ++ci){
            const float4 xv = *reinterpret_cast<const float4*>(
                x + (size_t)(b*C_CH + ci)*NPIX + n);
#pragma unroll
            for (int k = 0; k < 8; ++k){
                float wv_ = w[k*C_CH + ci];
                acc[k][0] = fmaf(xv.x, wv_, acc[k][0]);
                acc[k][1] = fmaf(xv.y, wv_, acc[k][1]);
                acc[k][2] = fmaf(xv.z, wv_, acc[k][2]);
                acc[k][3] = fmaf(xv.w, wv_, acc[k][3]);
            }
        }
        if (isq){  // fold log2(e) so softmax uses native exp2
#pragma unroll
            for (int k = 0; k < 8; ++k)
#pragma unroll
                for (int px = 0; px < 4; ++px) acc[k][px] *= 1.44269504f;
        }
        __hip_bfloat16* dst = isq ? qp : kp;
#pragma unroll
        for (int px = 0; px < 4; ++px){
            bf16x8 row;
#pragma unroll
            for (int k = 0; k < 8; ++k) row[k] = (short)bf16b(acc[k][px]);
            *reinterpret_cast<bf16x8*>(dst + ((size_t)(b*NPIX + n + px))*NQ) = row;
        }
    } else {
        int bc = blk - 180;                // (b*64+c)
        float s = 0.f;
        for (int i = tid; i < NPIX; i += 256) s += x[(size_t)bc*NPIX + i];
#pragma unroll
        for (int o = 32; o > 0; o >>= 1) s += __shfl_down(s, o, 64);
        __shared__ float red[4];
        if ((tid & 63) == 0) red[tid >> 6] = s;
        __syncthreads();
        if (tid == 0) amean[bc] = (red[0] + red[1] + red[2] + red[3]) * (1.f / (float)NPIX);
    }
}

// ---------- fused attention (32 q/block, 8 key-partition waves) + SE + tree combine ----------
__global__ __launch_bounds__(512, 4) void flash_fused(
    const __hip_bfloat16* __restrict__ qp,
    const __hip_bfloat16* __restrict__ kp,
    const __hip_bfloat16* __restrict__ vswz,
    const float* __restrict__ amean,
    const float* __restrict__ sw1, const float* __restrict__ sb1,
    const float* __restrict__ s1w, const float* __restrict__ s1b,
    const float* __restrict__ s1m, const float* __restrict__ s1v,
    const float* __restrict__ sw2, const float* __restrict__ sb2,
    const float* __restrict__ s2w, const float* __restrict__ s2b,
    const float* __restrict__ s2m, const float* __restrict__ s2v,
    const float* __restrict__ x,
    const float* __restrict__ gamma,
    const float* __restrict__ bnw, const float* __restrict__ bnb,
    const float* __restrict__ bnm, const float* __restrict__ bnv,
    float* __restrict__ out)
{
    __shared__ __align__(16) float sm[4*SM_F];   // 33280 B: 4 combine slots (tree)

    const int qt2 = blockIdx.x, b = blockIdx.y;   // 32 queries per block
    const int p  = threadIdx.x >> 6;     // wave = key partition (0..7)
    const int l  = threadIdx.x & 63;
    const int lq = l & 15;               // query column
    const int lg = l >> 4;               // lane group
    const int vlane = lq*32 + lg*8;      // bf16 offset of this lane's V frag in a 1KB tile

    // --- SE a1 (redundant per wave; independent of attention) ---
    float a1r;
    {
        int r8 = l & 7;
        float s = sb1[r8];
#pragma unroll 8
        for (int c = 0; c < C_CH; ++c)
            s = fmaf(amean[b*C_CH + c], sw1[r8*C_CH + c], s);
        s = (s - s1m[r8]) * (s1w[r8] * rsqrtf(s1v[r8] + 1e-5f)) + s1b[r8];
        a1r = fmaxf(s, 0.f);
    }

    bf16x8 zf = {0,0,0,0,0,0,0,0};
    bf16x8 qfrag[2];      // B-operand: B[d = lg*8+j][n = lq] for 2 q-tiles
#pragma unroll
    for (int qi = 0; qi < 2; ++qi){
        qfrag[qi] = zf;
        if (lg == 0)
            qfrag[qi] = *reinterpret_cast<const bf16x8*>(
                qp + (size_t)(b*NPIX + qt2*32 + qi*16 + lq) * NQ);
    }

    bf16x8 ones;          // bf16 1.0 x8 — constant A-frag for the L-denominator MFMA
#pragma unroll
    for (int i = 0; i < 8; ++i) ones[i] = (short)0x3F80;

    f32x4 Of[2][4];
#pragma unroll
    for (int qi = 0; qi < 2; ++qi)
#pragma unroll
        for (int i = 0; i < 4; ++i) Of[qi][i] = (f32x4){0.f, 0.f, 0.f, 0.f};
    f32x4 Lf[2];
    Lf[0] = (f32x4){0.f, 0.f, 0.f, 0.f};
    Lf[1] = (f32x4){0.f, 0.f, 0.f, 0.f};

    for (int ch = 0; ch < NCHUNK; ++ch){
        const int j0  = p*KEYS_P + ch*64;
        const int jcb = b*NJC + (j0 >> 5);          // global 32-key chunk index

        // --- K fragments (lane-group 0 holds the real K-dim) ---
        bf16x8 kf[4];
#pragma unroll
        for (int jt = 0; jt < 4; ++jt){
            kf[jt] = zf;
            if (lg == 0)
                kf[jt] = *reinterpret_cast<const bf16x8*>(kp + (size_t)(b*NPIX + j0 + jt*16 + lq) * NQ);
        }
        // --- V fragments: contiguous 1KB per (kc,ct) tile; reused for both q-tiles ---
        bf16x8 vf[2][4];
#pragma unroll
        for (int kc = 0; kc < 2; ++kc)
#pragma unroll
            for (int ct = 0; ct < 4; ++ct)
                vf[kc][ct] = *reinterpret_cast<const bf16x8*>(
                    vswz + ((size_t)((jcb + kc)*4 + ct))*512 + vlane);

#pragma unroll
        for (int qi = 0; qi < 2; ++qi){
            // --- S^T = K·Q^T : Sf[jt][r] = S[key j0+jt*16+lg*4+r][query lq] ---
            f32x4 Sf[4];
#pragma unroll
            for (int jt = 0; jt < 4; ++jt)
                Sf[jt] = __builtin_amdgcn_mfma_f32_16x16x32_bf16(kf[jt], qfrag[qi], (f32x4){0.f,0.f,0.f,0.f}, 0, 0, 0);

            // --- P = exp2(S); pack key-pairs: D[jt][i] holds pair-id jt*8+lg*2+i ---
            unsigned D[4][2];
#pragma unroll
            for (int jt = 0; jt < 4; ++jt){
                D[jt][0] = pack2bf(exp2f(Sf[jt][0]), exp2f(Sf[jt][1]));
                D[jt][1] = pack2bf(exp2f(Sf[jt][2]), exp2f(Sf[jt][3]));
            }

            // --- in-register P redistribution via permlane32/16 swaps ---
#pragma unroll
            for (int kc = 0; kc < 2; ++kc){
                unsigned o0, o1, o2, o3;
                {
                    uint2v r1 = __builtin_amdgcn_permlane32_swap(D[2*kc][0], D[2*kc+1][0], false, false);
                    uint2v r2 = __builtin_amdgcn_permlane16_swap(r1[0], r1[1], false, false);
                    o0 = r2[0]; o2 = r2[1];
                }
                {
                    uint2v r1 = __builtin_amdgcn_permlane32_swap(D[2*kc][1], D[2*kc+1][1], false, false);
                    uint2v r2 = __builtin_amdgcn_permlane16_swap(r1[0], r1[1], false, false);
                    o1 = r2[0]; o3 = r2[1];
                }
                u32x4 pu; pu[0] = o0; pu[1] = o1; pu[2] = o2; pu[3] = o3;
                bf16x8 pf = __builtin_bit_cast(bf16x8, pu);
#pragma unroll
                for (int ct = 0; ct < 4; ++ct)
                    Of[qi][ct] = __builtin_amdgcn_mfma_f32_16x16x32_bf16(vf[kc][ct], pf, Of[qi][ct], 0, 0, 0);
                Lf[qi] = __builtin_amdgcn_mfma_f32_16x16x32_bf16(ones, pf, Lf[qi], 0, 0, 0);
            }
        }
    }

    // --- tree combine: waves 4-7 write slots 0-3; waves 0-3 accumulate in ---
    if (p >= 4){
        const int ps = p - 4;
#pragma unroll
        for (int qi = 0; qi < 2; ++qi)
#pragma unroll
            for (int ct = 0; ct < 4; ++ct)
#pragma unroll
                for (int r = 0; r < 4; ++r)
                    sm[ps*SM_F + qi*1024 + (ct*4 + r)*64 + l] = Of[qi][ct][r];
        if (l < 16){
            sm[ps*SM_F + 2048 + lq]      = Lf[0][0];
            sm[ps*SM_F + 2048 + 16 + lq] = Lf[1][0];
        }
    }
    __syncthreads();
    if (p < 4){
#pragma unroll
        for (int qi = 0; qi < 2; ++qi)
#pragma unroll
            for (int ct = 0; ct < 4; ++ct)
#pragma unroll
                for (int r = 0; r < 4; ++r)
                    sm[p*SM_F + qi*1024 + (ct*4 + r)*64 + l] += Of[qi][ct][r];
        if (l < 16){
            sm[p*SM_F + 2048 + lq]      += Lf[0][0];
            sm[p*SM_F + 2048 + 16 + lq] += Lf[1][0];
        }
    }
    __syncthreads();

    // --- combine 4 slots + SE a2 + epilogue: out = x*(1+a2) + BN(gamma*O/L) ---
    {
        const int w8 = threadIdx.x >> 6;   // 0..7
        const int qi = w8 >> 2;            // q-tile
        const int ct = w8 & 3;             // channel tile: 4 channels x 1 pixel
        float gam = gamma[0];

        // SE a2 for this thread's 4 channels (gather a1 via shuffles)
        float a1g[8];
#pragma unroll
        for (int j = 0; j < 8; ++j) a1g[j] = __shfl(a1r, (l & 56) | j, 64);
        float a2v[4];
#pragma unroll
        for (int r = 0; r < 4; ++r){
            int c = ct*16 + lg*4 + r;
            float s = sb2[c];
#pragma unroll
            for (int j = 0; j < 8; ++j) s = fmaf(a1g[j], sw2[c*NQ + j], s);
            s = (s - s2m[c]) * (s2w[c] * rsqrtf(s2v[c] + 1e-5f)) + s2b[c];
            a2v[r] = fmaxf(s, 0.f);
        }

        float L = 0.f;
#pragma unroll
        for (int q = 0; q < 4; ++q) L += sm[q*SM_F + 2048 + qi*16 + lq];
        float invL = 1.f / L;
        int n = qt2*32 + qi*16 + lq;
#pragma unroll
        for (int r = 0; r < 4; ++r){
            float O = 0.f;
#pragma unroll
            for (int q = 0; q < 4; ++q) O += sm[q*SM_F + qi*1024 + (ct*4 + r)*64 + l];
            int c = ct*16 + lg*4 + r;
            float pam = gam * O * invL;
            pam = (pam - bnm[c]) * (bnw[c] * rsqrtf(bnv[c] + 1e-5f)) + bnb[c];
            float xv = x[(size_t)(b*C_CH + c)*NPIX + n];
            out[(size_t)(b*C_CH + c)*NPIX + n] = fmaf(xv, a2v[r], xv + pam);
        }
    }
}

extern "C" void kernel_launch(void* const* d_in, const int* in_sizes, int n_in,
                              void* d_out, int out_size, void* d_ws, size_t ws_size,
                              hipStream_t stream)
{
    const float* x     = (const float*)d_in[0];
    const float* wq    = (const float*)d_in[1];
    const float* bq    = (const float*)d_in[2];
    const float* wk    = (const float*)d_in[3];
    const float* bk    = (const float*)d_in[4];
    const float* wv    = (const float*)d_in[5];
    const float* bv    = (const float*)d_in[6];
    const float* gamma = (const float*)d_in[7];
    const float* bnw   = (const float*)d_in[8];
    const float* bnb   = (const float*)d_in[9];
    const float* bnm   = (const float*)d_in[10];
    const float* bnv   = (const float*)d_in[11];
    const float* sw1   = (const float*)d_in[12];
    const float* sb1   = (const float*)d_in[13];
    const float* s1w   = (const float*)d_in[14];
    const float* s1b   = (const float*)d_in[15];
    const float* s1m   = (const float*)d_in[16];
    const float* s1v   = (const float*)d_in[17];
    const float* sw2   = (const float*)d_in[18];
    const float* sb2   = (const float*)d_in[19];
    const float* s2w   = (const float*)d_in[20];
    const float* s2b   = (const float*)d_in[21];
    const float* s2m   = (const float*)d_in[22];
    const float* s2v   = (const float*)d_in[23];

    size_t off = 0;
    auto give = [&](size_t bytes) -> void* {
        void* r = (char*)d_ws + off;
        off += (bytes + 255) & ~(size_t)255;
        return r;
    };
    __hip_bfloat16* qp   = (__hip_bfloat16*)give((size_t)B_SZ*NPIX*NQ*2);
    __hip_bfloat16* kp   = (__hip_bfloat16*)give((size_t)B_SZ*NPIX*NQ*2);
    __hip_bfloat16* vswz = (__hip_bfloat16*)give((size_t)B_SZ*C_CH*NPIX*2);
    float* amean = (float*)give((size_t)B_SZ*C_CH*4);

    prep_kernel<<<dim3(308), dim3(256), 0, stream>>>(x, wq, bq, wk, bk, wv, bv,
                                                     qp, kp, vswz, amean);
    flash_fused<<<dim3(QBLKS, B_SZ), dim3(512), 0, stream>>>(
        qp, kp, vswz, amean,
        sw1, sb1, s1w, s1b, s1m, s1v,
        sw2, sb2, s2w, s2b, s2m, s2v,
        x, gamma, bnw, bnb, bnm, bnv, (float*)d_out);
}

// Round 5
// 204.645 us; speedup vs baseline: 1.0556x; 1.0347x over previous
//
#include <hip/hip_runtime.h>
#include <hip/hip_bf16.h>

#define B_SZ   2
#define C_CH   64
#define NQ     8          // q/k channels (C/8)
#define NPIX   9216       // 96*96
#define NJC    288        // NPIX/32 key 32-chunks per batch
#define QBLKS  288        // NPIX/32 query blocks (32 queries per block)
#define KPART  8          // key partitions, one per wave in a block
#define KEYS_P 1152       // NPIX/KPART
#define NCHUNK 18         // 64 keys per chunk
#define SM_F   2080       // per-slot combine floats: 2048 O + 32 L (4 slots, tree-combined)
#define NP4    2304       // NPIX/4
#define KSTEP  (64*NQ)    // kp elements per chunk
#define VSTEP  4096       // vswz elements per chunk (2 x 4 x 512)

typedef short bf16x8 __attribute__((ext_vector_type(8)));
typedef float f32x4  __attribute__((ext_vector_type(4)));
typedef unsigned u32x4 __attribute__((ext_vector_type(4)));
typedef unsigned uint2v __attribute__((ext_vector_type(2)));

// single-instruction packed f32->bf16 (RNE), a -> low16, b -> high16
static __device__ __forceinline__ unsigned pack2bf(float a, float b){
    unsigned r;
    asm("v_cvt_pk_bf16_f32 %0, %1, %2" : "=v"(r) : "v"(a), "v"(b));
    return r;
}

// ---------- fused prep, 8-channel register blocking ----------
__global__ __launch_bounds__(256) void prep_kernel(
    const float* __restrict__ x,
    const float* __restrict__ wq, const float* __restrict__ bq,
    const float* __restrict__ wk, const float* __restrict__ bk,
    const float* __restrict__ wv, const float* __restrict__ bv,
    __hip_bfloat16* __restrict__ qp, __hip_bfloat16* __restrict__ kp,
    __hip_bfloat16* __restrict__ vswz, float* __restrict__ amean)
{
    const int blk = blockIdx.x, tid = threadIdx.x;
    if (blk < 144){
        int t  = blk*256 + tid;            // (b, c8, n4)
        int n  = (t % NP4) * 4;
        int c8 = (t / NP4) & 7;            // wave-uniform (NP4 % 64 == 0)
        int b  = t / (NP4*8);
        c8 = __builtin_amdgcn_readfirstlane(c8);
        b  = __builtin_amdgcn_readfirstlane(b);
        float acc[8][4];
#pragma unroll
        for (int k = 0; k < 8; ++k){
            float bvv = bv[c8*8 + k];
            acc[k][0] = bvv; acc[k][1] = bvv; acc[k][2] = bvv; acc[k][3] = bvv;
        }
#pragma unroll 4
        for (int ci = 0; ci < C_CH; ++ci){
            const float4 xv = *reinterpret_cast<const float4*>(
                x + (size_t)(b*C_CH + ci)*NPIX + n);
#pragma unroll
            for (int k = 0; k < 8; ++k){
                float w = wv[(c8*8 + k)*C_CH + ci];
                acc[k][0] = fmaf(xv.x, w, acc[k][0]);
                acc[k][1] = fmaf(xv.y, w, acc[k][1]);
                acc[k][2] = fmaf(xv.z, w, acc[k][2]);
                acc[k][3] = fmaf(xv.w, w, acc[k][3]);
            }
        }
#pragma unroll
        for (int k = 0; k < 8; ++k){
            int c = c8*8 + k;
            size_t base = ((size_t)((b*NJC + (n >> 5))*4 + (c >> 4)))*512
                        + ((c & 15)*32) + (n & 31);
            unsigned long long wpk =
                (unsigned long long)pack2bf(acc[k][0], acc[k][1]) |
                ((unsigned long long)pack2bf(acc[k][2], acc[k][3]) << 32);
            *reinterpret_cast<unsigned long long*>(vswz + base) = wpk;
        }
    } else if (blk < 180){
        int t  = (blk - 144)*256 + tid;    // (b, o8, n4)
        int n  = (t % NP4) * 4;
        int o8 = (t / NP4) & 1;            // wave-uniform; 0 => q, 1 => k
        int b  = t / (NP4*2);
        o8 = __builtin_amdgcn_readfirstlane(o8);
        b  = __builtin_amdgcn_readfirstlane(b);
        const bool isq = (o8 == 0);
        const float* w    = isq ? wq : wk;
        const float* bias = isq ? bq : bk;
        float acc[8][4];
#pragma unroll
        for (int k = 0; k < 8; ++k){
            float bb = bias[k];
            acc[k][0] = bb; acc[k][1] = bb; acc[k][2] = bb; acc[k][3] = bb;
        }
#pragma unroll 4
        for (int ci = 0; ci < C_CH; ++ci){
            const float4 xv = *reinterpret_cast<const float4*>(
                x + (size_t)(b*C_CH + ci)*NPIX + n);
#pragma unroll
            for (int k = 0; k < 8; ++k){
                float wv_ = w[k*C_CH + ci];
                acc[k][0] = fmaf(xv.x, wv_, acc[k][0]);
                acc[k][1] = fmaf(xv.y, wv_, acc[k][1]);
                acc[k][2] = fmaf(xv.z, wv_, acc[k][2]);
                acc[k][3] = fmaf(xv.w, wv_, acc[k][3]);
            }
        }
        if (isq){  // fold log2(e) so softmax uses native exp2
#pragma unroll
            for (int k = 0; k < 8; ++k)
#pragma unroll
                for (int px = 0; px < 4; ++px) acc[k][px] *= 1.44269504f;
        }
        __hip_bfloat16* dst = isq ? qp : kp;
#pragma unroll
        for (int px = 0; px < 4; ++px){
            u32x4 row;
            row[0] = pack2bf(acc[0][px], acc[1][px]);
            row[1] = pack2bf(acc[2][px], acc[3][px]);
            row[2] = pack2bf(acc[4][px], acc[5][px]);
            row[3] = pack2bf(acc[6][px], acc[7][px]);
            *reinterpret_cast<u32x4*>(dst + ((size_t)(b*NPIX + n + px))*NQ) = row;
        }
    } else {
        int bc = blk - 180;                // (b*64+c)
        float s = 0.f;
        for (int i = tid; i < NPIX; i += 256) s += x[(size_t)bc*NPIX + i];
#pragma unroll
        for (int o = 32; o > 0; o >>= 1) s += __shfl_down(s, o, 64);
        __shared__ float red[4];
        if ((tid & 63) == 0) red[tid >> 6] = s;
        __syncthreads();
        if (tid == 0) amean[bc] = (red[0] + red[1] + red[2] + red[3]) * (1.f / (float)NPIX);
    }
}

// ---------- fused attention (32 q/block, 8 waves), ping-pong prefetch, in-reg P ----------
__global__ __launch_bounds__(512, 2) void flash_fused(
    const __hip_bfloat16* __restrict__ qp,
    const __hip_bfloat16* __restrict__ kp,
    const __hip_bfloat16* __restrict__ vswz,
    const float* __restrict__ amean,
    const float* __restrict__ sw1, const float* __restrict__ sb1,
    const float* __restrict__ s1w, const float* __restrict__ s1b,
    const float* __restrict__ s1m, const float* __restrict__ s1v,
    const float* __restrict__ sw2, const float* __restrict__ sb2,
    const float* __restrict__ s2w, const float* __restrict__ s2b,
    const float* __restrict__ s2m, const float* __restrict__ s2v,
    const float* __restrict__ x,
    const float* __restrict__ gamma,
    const float* __restrict__ bnw, const float* __restrict__ bnb,
    const float* __restrict__ bnm, const float* __restrict__ bnv,
    float* __restrict__ out)
{
    __shared__ __align__(16) float sm[4*SM_F];   // 33280 B: 4 combine slots (tree)

    const int qt2 = blockIdx.x, b = blockIdx.y;   // 32 queries per block
    const int p  = threadIdx.x >> 6;     // wave = key partition (0..7)
    const int l  = threadIdx.x & 63;
    const int lq = l & 15;               // query column
    const int lg = l >> 4;               // lane group
    const int vlane = lq*32 + lg*8;      // bf16 offset of this lane's V frag in a 1KB tile

    bf16x8 zf = {0,0,0,0,0,0,0,0};
    bf16x8 qfrag[2];      // B-operand: B[d = lg*8+j][n = lq] for 2 q-tiles
#pragma unroll
    for (int qi = 0; qi < 2; ++qi){
        qfrag[qi] = zf;
        if (lg == 0)
            qfrag[qi] = *reinterpret_cast<const bf16x8*>(
                qp + (size_t)(b*NPIX + qt2*32 + qi*16 + lq) * NQ);
    }

    bf16x8 ones;          // bf16 1.0 x8 — constant A-frag for the L-denominator MFMA
#pragma unroll
    for (int i = 0; i < 8; ++i) ones[i] = (short)0x3F80;

    f32x4 Of[2][4];
#pragma unroll
    for (int qi = 0; qi < 2; ++qi)
#pragma unroll
        for (int i = 0; i < 4; ++i) Of[qi][i] = (f32x4){0.f, 0.f, 0.f, 0.f};
    f32x4 Lf[2];
    Lf[0] = (f32x4){0.f, 0.f, 0.f, 0.f};
    Lf[1] = (f32x4){0.f, 0.f, 0.f, 0.f};

    // running pointers (advance one chunk per prefetch-issue)
    const __hip_bfloat16* kptr = kp + ((size_t)(b*NPIX + p*KEYS_P + lq))*NQ;
    const __hip_bfloat16* vptr = vswz + ((size_t)(b*NJC + p*(KEYS_P/32)))*4*512 + vlane;

    bf16x8 kfa[4], vfa[2][4];
    bf16x8 kfb[4], vfb[2][4];

    auto loadK = [&](bf16x8 (&dst)[4], const __hip_bfloat16* ptr){
#pragma unroll
        for (int jt = 0; jt < 4; ++jt){
            dst[jt] = zf;
            if (lg == 0)
                dst[jt] = *reinterpret_cast<const bf16x8*>(ptr + jt*16*NQ);
        }
    };
    auto loadV = [&](bf16x8 (&dst)[2][4], const __hip_bfloat16* ptr){
#pragma unroll
        for (int kc = 0; kc < 2; ++kc)
#pragma unroll
            for (int ct = 0; ct < 4; ++ct)
                dst[kc][ct] = *reinterpret_cast<const bf16x8*>(ptr + (kc*4 + ct)*512);
    };
    auto compute = [&](bf16x8 (&kfc)[4], bf16x8 (&vfc)[2][4]){
#pragma unroll
        for (int qi = 0; qi < 2; ++qi){
            // S^T = K·Q^T : Sf[jt][r] = S[key jt*16+lg*4+r][query lq]
            f32x4 Sf[4];
#pragma unroll
            for (int jt = 0; jt < 4; ++jt)
                Sf[jt] = __builtin_amdgcn_mfma_f32_16x16x32_bf16(kfc[jt], qfrag[qi], (f32x4){0.f,0.f,0.f,0.f}, 0, 0, 0);
            // P = exp2(S); cvt_pk key pairs: D[jt][i] holds pair-id jt*8+lg*2+i
            unsigned D[4][2];
#pragma unroll
            for (int jt = 0; jt < 4; ++jt){
                D[jt][0] = pack2bf(exp2f(Sf[jt][0]), exp2f(Sf[jt][1]));
                D[jt][1] = pack2bf(exp2f(Sf[jt][2]), exp2f(Sf[jt][3]));
            }
            // in-register P redistribution via permlane32/16 swaps
#pragma unroll
            for (int kc = 0; kc < 2; ++kc){
                unsigned o0, o1, o2, o3;
                {
                    uint2v r1 = __builtin_amdgcn_permlane32_swap(D[2*kc][0], D[2*kc+1][0], false, false);
                    uint2v r2 = __builtin_amdgcn_permlane16_swap(r1[0], r1[1], false, false);
                    o0 = r2[0]; o2 = r2[1];
                }
                {
                    uint2v r1 = __builtin_amdgcn_permlane32_swap(D[2*kc][1], D[2*kc+1][1], false, false);
                    uint2v r2 = __builtin_amdgcn_permlane16_swap(r1[0], r1[1], false, false);
                    o1 = r2[0]; o3 = r2[1];
                }
                u32x4 pu; pu[0] = o0; pu[1] = o1; pu[2] = o2; pu[3] = o3;
                bf16x8 pf = __builtin_bit_cast(bf16x8, pu);
#pragma unroll
                for (int ct = 0; ct < 4; ++ct)
                    Of[qi][ct] = __builtin_amdgcn_mfma_f32_16x16x32_bf16(vfc[kc][ct], pf, Of[qi][ct], 0, 0, 0);
                Lf[qi] = __builtin_amdgcn_mfma_f32_16x16x32_bf16(ones, pf, Lf[qi], 0, 0, 0);
            }
        }
    };

    // prologue: chunk 0 into A
    loadK(kfa, kptr); loadV(vfa, vptr);
    kptr += KSTEP; vptr += VSTEP;

    // steady state: 8 iterations cover chunks 0..15 (prefetch 1..16)
    for (int it = 0; it < (NCHUNK - 2)/2; ++it){
        loadK(kfb, kptr); loadV(vfb, vptr);     // odd chunk
        kptr += KSTEP; vptr += VSTEP;
        compute(kfa, vfa);
        loadK(kfa, kptr); loadV(vfa, vptr);     // even chunk
        kptr += KSTEP; vptr += VSTEP;
        compute(kfb, vfb);
    }
    // tail: chunk 16 in A; load+compute 17
    loadK(kfb, kptr); loadV(vfb, vptr);
    compute(kfa, vfa);
    compute(kfb, vfb);

    // --- SE a1 (after hot loop; only needs amean) ---
    float a1r;
    {
        int r8 = l & 7;
        float s = sb1[r8];
#pragma unroll 8
        for (int c = 0; c < C_CH; ++c)
            s = fmaf(amean[b*C_CH + c], sw1[r8*C_CH + c], s);
        s = (s - s1m[r8]) * (s1w[r8] * rsqrtf(s1v[r8] + 1e-5f)) + s1b[r8];
        a1r = fmaxf(s, 0.f);
    }

    // --- tree combine: waves 4-7 write slots 0-3; waves 0-3 accumulate in ---
    if (p >= 4){
        const int ps = p - 4;
#pragma unroll
        for (int qi = 0; qi < 2; ++qi)
#pragma unroll
            for (int ct = 0; ct < 4; ++ct)
#pragma unroll
                for (int r = 0; r < 4; ++r)
                    sm[ps*SM_F + qi*1024 + (ct*4 + r)*64 + l] = Of[qi][ct][r];
        if (l < 16){
            sm[ps*SM_F + 2048 + lq]      = Lf[0][0];
            sm[ps*SM_F + 2048 + 16 + lq] = Lf[1][0];
        }
    }
    __syncthreads();
    if (p < 4){
#pragma unroll
        for (int qi = 0; qi < 2; ++qi)
#pragma unroll
            for (int ct = 0; ct < 4; ++ct)
#pragma unroll
                for (int r = 0; r < 4; ++r)
                    sm[p*SM_F + qi*1024 + (ct*4 + r)*64 + l] += Of[qi][ct][r];
        if (l < 16){
            sm[p*SM_F + 2048 + lq]      += Lf[0][0];
            sm[p*SM_F + 2048 + 16 + lq] += Lf[1][0];
        }
    }
    __syncthreads();

    // --- combine 4 slots + SE a2 + epilogue: out = x*(1+a2) + BN(gamma*O/L) ---
    {
        const int w8 = threadIdx.x >> 6;   // 0..7
        const int qi = w8 >> 2;            // q-tile
        const int ct = w8 & 3;             // channel tile: 4 channels x 1 pixel
        float gam = gamma[0];

        // SE a2 for this thread's 4 channels (gather a1 via shuffles)
        float a1g[8];
#pragma unroll
        for (int j = 0; j < 8; ++j) a1g[j] = __shfl(a1r, (l & 56) | j, 64);
        float a2v[4];
#pragma unroll
        for (int r = 0; r < 4; ++r){
            int c = ct*16 + lg*4 + r;
            float s = sb2[c];
#pragma unroll
            for (int j = 0; j < 8; ++j) s = fmaf(a1g[j], sw2[c*NQ + j], s);
            s = (s - s2m[c]) * (s2w[c] * rsqrtf(s2v[c] + 1e-5f)) + s2b[c];
            a2v[r] = fmaxf(s, 0.f);
        }

        float L = 0.f;
#pragma unroll
        for (int q = 0; q < 4; ++q) L += sm[q*SM_F + 2048 + qi*16 + lq];
        float invL = 1.f / L;
        int n = qt2*32 + qi*16 + lq;
#pragma unroll
        for (int r = 0; r < 4; ++r){
            float O = 0.f;
#pragma unroll
            for (int q = 0; q < 4; ++q) O += sm[q*SM_F + qi*1024 + (ct*4 + r)*64 + l];
            int c = ct*16 + lg*4 + r;
            float pam = gam * O * invL;
            pam = (pam - bnm[c]) * (bnw[c] * rsqrtf(bnv[c] + 1e-5f)) + bnb[c];
            float xv = x[(size_t)(b*C_CH + c)*NPIX + n];
            out[(size_t)(b*C_CH + c)*NPIX + n] = fmaf(xv, a2v[r], xv + pam);
        }
    }
}

extern "C" void kernel_launch(void* const* d_in, const int* in_sizes, int n_in,
                              void* d_out, int out_size, void* d_ws, size_t ws_size,
                              hipStream_t stream)
{
    const float* x     = (const float*)d_in[0];
    const float* wq    = (const float*)d_in[1];
    const float* bq    = (const float*)d_in[2];
    const float* wk    = (const float*)d_in[3];
    const float* bk    = (const float*)d_in[4];
    const float* wv    = (const float*)d_in[5];
    const float* bv    = (const float*)d_in[6];
    const float* gamma = (const float*)d_in[7];
    const float* bnw   = (const float*)d_in[8];
    const float* bnb   = (const float*)d_in[9];
    const float* bnm   = (const float*)d_in[10];
    const float* bnv   = (const float*)d_in[11];
    const float* sw1   = (const float*)d_in[12];
    const float* sb1   = (const float*)d_in[13];
    const float* s1w   = (const float*)d_in[14];
    const float* s1b   = (const float*)d_in[15];
    const float* s1m   = (const float*)d_in[16];
    const float* s1v   = (const float*)d_in[17];
    const float* sw2   = (const float*)d_in[18];
    const float* sb2   = (const float*)d_in[19];
    const float* s2w   = (const float*)d_in[20];
    const float* s2b   = (const float*)d_in[21];
    const float* s2m   = (const float*)d_in[22];
    const float* s2v   = (const float*)d_in[23];

    size_t off = 0;
    auto give = [&](size_t bytes) -> void* {
        void* r = (char*)d_ws + off;
        off += (bytes + 255) & ~(size_t)255;
        return r;
    };
    __hip_bfloat16* qp   = (__hip_bfloat16*)give((size_t)B_SZ*NPIX*NQ*2);
    __hip_bfloat16* kp   = (__hip_bfloat16*)give((size_t)B_SZ*NPIX*NQ*2);
    __hip_bfloat16* vswz = (__hip_bfloat16*)give((size_t)B_SZ*C_CH*NPIX*2);
    float* amean = (float*)give((size_t)B_SZ*C_CH*4);

    prep_kernel<<<dim3(308), dim3(256), 0, stream>>>(x, wq, bq, wk, bk, wv, bv,
                                                     qp, kp, vswz, amean);
    flash_fused<<<dim3(QBLKS, B_SZ), dim3(512), 0, stream>>>(
        qp, kp, vswz, amean,
        sw1, sb1, s1w, s1b, s1m, s1v,
        sw2, sb2, s2w, s2b, s2m, s2v,
        x, gamma, bnw, bnb, bnm, bnv, (float*)d_out);
}

// Round 6
// 192.877 us; speedup vs baseline: 1.1200x; 1.0610x over previous
//
#include <hip/hip_runtime.h>
#include <hip/hip_bf16.h>

#define B_SZ   2
#define C_CH   64
#define NQ     8          // q/k real channels (C/8)
#define QKS    16         // q/k stored stride (zero-padded to MFMA K)
#define NPIX   9216       // 96*96
#define NKS    576        // NPIX/16 key 16-slices per batch
#define QBLKS  288        // NPIX/32 query blocks (32 queries per block)
#define KPART  8          // key partitions, one per wave in a block
#define KEYS_P 1152       // NPIX/KPART
#define NCHUNK 18         // 64 keys per chunk
#define SM_F   2080       // per-slot combine floats: 2048 O + 32 L (4 slots, tree)
#define NP4    2304       // NPIX/4
#define KSTEP2 1024       // kp elements per 64-key chunk (64*16)
#define VSTEP  4096       // vswz elements per chunk (4 kslices x 2 ctiles x 512)

typedef short bf16x8 __attribute__((ext_vector_type(8)));
typedef float f32x4  __attribute__((ext_vector_type(4)));
typedef float f32x16 __attribute__((ext_vector_type(16)));
typedef unsigned u32x4 __attribute__((ext_vector_type(4)));
typedef unsigned uint2v __attribute__((ext_vector_type(2)));

// single-instruction packed f32->bf16 (RNE), a -> low16, b -> high16
static __device__ __forceinline__ unsigned pack2bf(float a, float b){
    unsigned r;
    asm("v_cvt_pk_bf16_f32 %0, %1, %2" : "=v"(r) : "v"(a), "v"(b));
    return r;
}

// ---------- fused prep, 8-channel register blocking ----------
// blocks [0,144):    proj_v  thread = (b, c8, n4): 4 px, 8 channels
// blocks [144,180):  proj_qk thread = (b, o8, n4): 4 px, all 8 q or k outputs
// blocks [180,308):  GAP
// V pre-swizzled into 32x32x16 MFMA-A-fragment order (1KB tiles):
//   tile (b, ks=n/16, ct=c/32), elem: lane=(n%16)/8*32 + (c%32), e=n%8
// q/k stored with stride 16, dims 8..15 zeroed (so MFMA frags load unmasked).
__global__ __launch_bounds__(256) void prep_kernel(
    const float* __restrict__ x,
    const float* __restrict__ wq, const float* __restrict__ bq,
    const float* __restrict__ wk, const float* __restrict__ bk,
    const float* __restrict__ wv, const float* __restrict__ bv,
    __hip_bfloat16* __restrict__ qp, __hip_bfloat16* __restrict__ kp,
    __hip_bfloat16* __restrict__ vswz, float* __restrict__ amean)
{
    const int blk = blockIdx.x, tid = threadIdx.x;
    if (blk < 144){
        int t  = blk*256 + tid;            // (b, c8, n4)
        int n  = (t % NP4) * 4;
        int c8 = (t / NP4) & 7;            // wave-uniform (NP4 % 64 == 0)
        int b  = t / (NP4*8);
        c8 = __builtin_amdgcn_readfirstlane(c8);
        b  = __builtin_amdgcn_readfirstlane(b);
        float acc[8][4];
#pragma unroll
        for (int k = 0; k < 8; ++k){
            float bvv = bv[c8*8 + k];
            acc[k][0] = bvv; acc[k][1] = bvv; acc[k][2] = bvv; acc[k][3] = bvv;
        }
#pragma unroll 4
        for (int ci = 0; ci < C_CH; ++ci){
            const float4 xv = *reinterpret_cast<const float4*>(
                x + (size_t)(b*C_CH + ci)*NPIX + n);
#pragma unroll
            for (int k = 0; k < 8; ++k){
                float w = wv[(c8*8 + k)*C_CH + ci];
                acc[k][0] = fmaf(xv.x, w, acc[k][0]);
                acc[k][1] = fmaf(xv.y, w, acc[k][1]);
                acc[k][2] = fmaf(xv.z, w, acc[k][2]);
                acc[k][3] = fmaf(xv.w, w, acc[k][3]);
            }
        }
#pragma unroll
        for (int k = 0; k < 8; ++k){
            int c = c8*8 + k;
            size_t base = ((size_t)((b*NKS + (n >> 4))*2 + (c >> 5)))*512
                        + (((n >> 3) & 1) << 8) + ((c & 31) << 3) + (n & 7);
            unsigned long long wpk =
                (unsigned long long)pack2bf(acc[k][0], acc[k][1]) |
                ((unsigned long long)pack2bf(acc[k][2], acc[k][3]) << 32);
            *reinterpret_cast<unsigned long long*>(vswz + base) = wpk;
        }
    } else if (blk < 180){
        int t  = (blk - 144)*256 + tid;    // (b, o8, n4)
        int n  = (t % NP4) * 4;
        int o8 = (t / NP4) & 1;            // wave-uniform; 0 => q, 1 => k
        int b  = t / (NP4*2);
        o8 = __builtin_amdgcn_readfirstlane(o8);
        b  = __builtin_amdgcn_readfirstlane(b);
        const bool isq = (o8 == 0);
        const float* w    = isq ? wq : wk;
        const float* bias = isq ? bq : bk;
        float acc[8][4];
#pragma unroll
        for (int k = 0; k < 8; ++k){
            float bb = bias[k];
            acc[k][0] = bb; acc[k][1] = bb; acc[k][2] = bb; acc[k][3] = bb;
        }
#pragma unroll 4
        for (int ci = 0; ci < C_CH; ++ci){
            const float4 xv = *reinterpret_cast<const float4*>(
                x + (size_t)(b*C_CH + ci)*NPIX + n);
#pragma unroll
            for (int k = 0; k < 8; ++k){
                float wv_ = w[k*C_CH + ci];
                acc[k][0] = fmaf(xv.x, wv_, acc[k][0]);
                acc[k][1] = fmaf(xv.y, wv_, acc[k][1]);
                acc[k][2] = fmaf(xv.z, wv_, acc[k][2]);
                acc[k][3] = fmaf(xv.w, wv_, acc[k][3]);
            }
        }
        if (isq){  // fold log2(e) so softmax uses native exp2
#pragma unroll
            for (int k = 0; k < 8; ++k)
#pragma unroll
                for (int px = 0; px < 4; ++px) acc[k][px] *= 1.44269504f;
        }
        __hip_bfloat16* dst = isq ? qp : kp;
        u32x4 zr; zr[0] = 0; zr[1] = 0; zr[2] = 0; zr[3] = 0;
#pragma unroll
        for (int px = 0; px < 4; ++px){
            u32x4 row;
            row[0] = pack2bf(acc[0][px], acc[1][px]);
            row[1] = pack2bf(acc[2][px], acc[3][px]);
            row[2] = pack2bf(acc[4][px], acc[5][px]);
            row[3] = pack2bf(acc[6][px], acc[7][px]);
            __hip_bfloat16* d0 = dst + ((size_t)(b*NPIX + n + px))*QKS;
            *reinterpret_cast<u32x4*>(d0)     = row;
            *reinterpret_cast<u32x4*>(d0 + 8) = zr;   // zero pad dims 8..15
        }
    } else {
        int bc = blk - 180;                // (b*64+c)
        float s = 0.f;
        for (int i = tid; i < NPIX; i += 256) s += x[(size_t)bc*NPIX + i];
#pragma unroll
        for (int o = 32; o > 0; o >>= 1) s += __shfl_down(s, o, 64);
        __shared__ float red[4];
        if ((tid & 63) == 0) red[tid >> 6] = s;
        __syncthreads();
        if (tid == 0) amean[bc] = (red[0] + red[1] + red[2] + red[3]) * (1.f / (float)NPIX);
    }
}

// ---------- fused attention: 32x32x16 MFMA path, 8 key-partition waves ----------
__global__ __launch_bounds__(512) void flash_fused(
    const __hip_bfloat16* __restrict__ qp,
    const __hip_bfloat16* __restrict__ kp,
    const __hip_bfloat16* __restrict__ vswz,
    const float* __restrict__ amean,
    const float* __restrict__ sw1, const float* __restrict__ sb1,
    const float* __restrict__ s1w, const float* __restrict__ s1b,
    const float* __restrict__ s1m, const float* __restrict__ s1v,
    const float* __restrict__ sw2, const float* __restrict__ sb2,
    const float* __restrict__ s2w, const float* __restrict__ s2b,
    const float* __restrict__ s2m, const float* __restrict__ s2v,
    const float* __restrict__ x,
    const float* __restrict__ gamma,
    const float* __restrict__ bnw, const float* __restrict__ bnb,
    const float* __restrict__ bnm, const float* __restrict__ bnv,
    float* __restrict__ out)
{
    __shared__ __align__(16) float sm[4*SM_F];   // 33280 B: 4 combine slots (tree)

    const int qt2 = blockIdx.x, b = blockIdx.y;   // 32 queries per block
    const int p  = threadIdx.x >> 6;     // wave = key partition (0..7)
    const int l  = threadIdx.x & 63;
    const int lc = l & 31;               // column lane (query / channel)
    const int lh = l >> 5;               // lane half (k-elem group)

    // Q fragment: B-operand, B[k=(lh*8+e)][col=query lc]; pad dims read zeros
    bf16x8 qfrag = *reinterpret_cast<const bf16x8*>(
        qp + ((size_t)(b*NPIX + qt2*32 + lc))*QKS + lh*8);

    bf16x8 ones;          // bf16 1.0 x8 — A-frag for the L-denominator MFMA
#pragma unroll
    for (int i = 0; i < 8; ++i) ones[i] = (short)0x3F80;

    f32x16 zero16;
#pragma unroll
    for (int i = 0; i < 16; ++i) zero16[i] = 0.f;

    f32x16 Of0 = zero16, Of1 = zero16;   // O^T accum: [channel row][query col], 2 ctiles
    f32x16 Lacc = zero16;                // L accum (all rows identical)

    // running pointers
    const __hip_bfloat16* kptr = kp + ((size_t)(b*NPIX + p*KEYS_P + lc))*QKS + lh*8;
    const __hip_bfloat16* vptr = vswz + ((size_t)((b*NKS + p*(KEYS_P/16))*2))*512 + l*8;

    auto CHUNK = [&](const bf16x8& k0, const bf16x8& k1){
        // V tiles for this chunk (issued first; consumed after QK+exp2 — self-hiding)
        bf16x8 vf[8];
#pragma unroll
        for (int t = 0; t < 8; ++t)
            vf[t] = *reinterpret_cast<const bf16x8*>(vptr + t*512);
        vptr += VSTEP;

        // QK^T per 32-key tile; P = exp2(S); cvt_pk into row-pair dwords
        unsigned D[16];
#pragma unroll
        for (int kt = 0; kt < 2; ++kt){
            f32x16 s = __builtin_amdgcn_mfma_f32_32x32x16_bf16(
                kt ? k1 : k0, qfrag, zero16, 0, 0, 0);
#pragma unroll
            for (int g = 0; g < 4; ++g){
                float e0 = exp2f(s[4*g+0]), e1 = exp2f(s[4*g+1]);
                float e2 = exp2f(s[4*g+2]), e3 = exp2f(s[4*g+3]);
                D[kt*8 + g*2 + 0] = pack2bf(e0, e1);
                D[kt*8 + g*2 + 1] = pack2bf(e2, e3);
            }
        }
        // per 16-key slice: build PV B-frag with 2 permlane32_swaps, then MFMA
#pragma unroll
        for (int ks = 0; ks < 4; ++ks){
            const int base = (ks >> 1)*8 + (ks & 1)*4;
            uint2v r0 = __builtin_amdgcn_permlane32_swap(D[base+0], D[base+2], false, false);
            uint2v r1 = __builtin_amdgcn_permlane32_swap(D[base+1], D[base+3], false, false);
            u32x4 pu; pu[0] = r0[0]; pu[1] = r1[0]; pu[2] = r0[1]; pu[3] = r1[1];
            bf16x8 pf = __builtin_bit_cast(bf16x8, pu);
            Of0  = __builtin_amdgcn_mfma_f32_32x32x16_bf16(vf[ks*2+0], pf, Of0, 0, 0, 0);
            Of1  = __builtin_amdgcn_mfma_f32_32x32x16_bf16(vf[ks*2+1], pf, Of1, 0, 0, 0);
            Lacc = __builtin_amdgcn_mfma_f32_32x32x16_bf16(ones,       pf, Lacc, 0, 0, 0);
        }
    };

    // K ping-pong: prologue chunk 0
    bf16x8 kA0 = *reinterpret_cast<const bf16x8*>(kptr);
    bf16x8 kA1 = *reinterpret_cast<const bf16x8*>(kptr + 512);
    kptr += KSTEP2;
    bf16x8 kB0, kB1;
    for (int it = 0; it < (NCHUNK - 2)/2; ++it){
        kB0 = *reinterpret_cast<const bf16x8*>(kptr);
        kB1 = *reinterpret_cast<const bf16x8*>(kptr + 512);
        kptr += KSTEP2;
        CHUNK(kA0, kA1);
        kA0 = *reinterpret_cast<const bf16x8*>(kptr);
        kA1 = *reinterpret_cast<const bf16x8*>(kptr + 512);
        kptr += KSTEP2;
        CHUNK(kB0, kB1);
    }
    kB0 = *reinterpret_cast<const bf16x8*>(kptr);
    kB1 = *reinterpret_cast<const bf16x8*>(kptr + 512);
    CHUNK(kA0, kA1);
    CHUNK(kB0, kB1);

    // --- SE a1 (after hot loop; only needs amean) ---
    float a1r;
    {
        int r8 = l & 7;
        float s = sb1[r8];
#pragma unroll 8
        for (int c = 0; c < C_CH; ++c)
            s = fmaf(amean[b*C_CH + c], sw1[r8*C_CH + c], s);
        s = (s - s1m[r8]) * (s1w[r8] * rsqrtf(s1v[r8] + 1e-5f)) + s1b[r8];
        a1r = fmaxf(s, 0.f);
    }

    // --- tree combine: waves 4-7 write slots 0-3; waves 0-3 accumulate in ---
    if (p >= 4){
        const int ps = p - 4;
#pragma unroll
        for (int r = 0; r < 16; ++r){
            sm[ps*SM_F +        r*64 + l] = Of0[r];
            sm[ps*SM_F + 1024 + r*64 + l] = Of1[r];
        }
        if (l < 32) sm[ps*SM_F + 2048 + l] = Lacc[0];
    }
    __syncthreads();
    if (p < 4){
#pragma unroll
        for (int r = 0; r < 16; ++r){
            sm[p*SM_F +        r*64 + l] += Of0[r];
            sm[p*SM_F + 1024 + r*64 + l] += Of1[r];
        }
        if (l < 32) sm[p*SM_F + 2048 + l] += Lacc[0];
    }
    __syncthreads();

    // --- combine 4 slots + SE a2 + epilogue: out = x*(1+a2) + BN(gamma*O/L) ---
    {
        const int w8 = threadIdx.x >> 6;   // 0..7
        const int i  = lc;                 // query
        const int cg = w8*2 + lh;          // channel group (0..15), 4 channels each
        float gam = gamma[0];

        // SE a2 for this thread's 4 channels (gather a1 via shuffles)
        float a1g[8];
#pragma unroll
        for (int j = 0; j < 8; ++j) a1g[j] = __shfl(a1r, (l & 56) | j, 64);
        float a2v[4];
#pragma unroll
        for (int r = 0; r < 4; ++r){
            int c = cg*4 + r;
            float s = sb2[c];
#pragma unroll
            for (int j = 0; j < 8; ++j) s = fmaf(a1g[j], sw2[c*NQ + j], s);
            s = (s - s2m[c]) * (s2w[c] * rsqrtf(s2v[c] + 1e-5f)) + s2b[c];
            a2v[r] = fmaxf(s, 0.f);
        }

        float L = 0.f;
#pragma unroll
        for (int q = 0; q < 4; ++q) L += sm[q*SM_F + 2048 + i];
        float invL = 1.f / L;
        int n = qt2*32 + i;
#pragma unroll
        for (int r = 0; r < 4; ++r){
            int c = cg*4 + r;
            // channel -> (ctile, reg, lane-half) in the 32x32 C layout
            int c5   = c & 31;
            int reg  = (c5 & 3) + 4*(c5 >> 3);
            int lsrc = (c5 >> 2) & 1;
            int o    = (c >> 5)*1024 + reg*64 + lsrc*32 + i;
            float O = 0.f;
#pragma unroll
            for (int q = 0; q < 4; ++q) O += sm[q*SM_F + o];
            float pam = gam * O * invL;
            pam = (pam - bnm[c]) * (bnw[c] * rsqrtf(bnv[c] + 1e-5f)) + bnb[c];
            float xv = x[(size_t)(b*C_CH + c)*NPIX + n];
            out[(size_t)(b*C_CH + c)*NPIX + n] = fmaf(xv, a2v[r], xv + pam);
        }
    }
}

extern "C" void kernel_launch(void* const* d_in, const int* in_sizes, int n_in,
                              void* d_out, int out_size, void* d_ws, size_t ws_size,
                              hipStream_t stream)
{
    const float* x     = (const float*)d_in[0];
    const float* wq    = (const float*)d_in[1];
    const float* bq    = (const float*)d_in[2];
    const float* wk    = (const float*)d_in[3];
    const float* bk    = (const float*)d_in[4];
    const float* wv    = (const float*)d_in[5];
    const float* bv    = (const float*)d_in[6];
    const float* gamma = (const float*)d_in[7];
    const float* bnw   = (const float*)d_in[8];
    const float* bnb   = (const float*)d_in[9];
    const float* bnm   = (const float*)d_in[10];
    const float* bnv   = (const float*)d_in[11];
    const float* sw1   = (const float*)d_in[12];
    const float* sb1   = (const float*)d_in[13];
    const float* s1w   = (const float*)d_in[14];
    const float* s1b   = (const float*)d_in[15];
    const float* s1m   = (const float*)d_in[16];
    const float* s1v   = (const float*)d_in[17];
    const float* sw2   = (const float*)d_in[18];
    const float* sb2   = (const float*)d_in[19];
    const float* s2w   = (const float*)d_in[20];
    const float* s2b   = (const float*)d_in[21];
    const float* s2m   = (const float*)d_in[22];
    const float* s2v   = (const float*)d_in[23];

    size_t off = 0;
    auto give = [&](size_t bytes) -> void* {
        void* r = (char*)d_ws + off;
        off += (bytes + 255) & ~(size_t)255;
        return r;
    };
    __hip_bfloat16* qp   = (__hip_bfloat16*)give((size_t)B_SZ*NPIX*QKS*2);
    __hip_bfloat16* kp   = (__hip_bfloat16*)give((size_t)B_SZ*NPIX*QKS*2);
    __hip_bfloat16* vswz = (__hip_bfloat16*)give((size_t)B_SZ*C_CH*NPIX*2);
    float* amean = (float*)give((size_t)B_SZ*C_CH*4);

    prep_kernel<<<dim3(308), dim3(256), 0, stream>>>(x, wq, bq, wk, bk, wv, bv,
                                                     qp, kp, vswz, amean);
    flash_fused<<<dim3(QBLKS, B_SZ), dim3(512), 0, stream>>>(
        qp, kp, vswz, amean,
        sw1, sb1, s1w, s1b, s1m, s1v,
        sw2, sb2, s2w, s2b, s2m, s2v,
        x, gamma, bnw, bnb, bnm, bnv, (float*)d_out);
}

// Round 7
// 171.417 us; speedup vs baseline: 1.2603x; 1.1252x over previous
//
#include <hip/hip_runtime.h>
#include <hip/hip_bf16.h>

#define B_SZ   2
#define C_CH   64
#define NQ     8          // q/k real channels (C/8)
#define QKS    16         // q/k stored stride (zero-padded to MFMA K)
#define NPIX   9216       // 96*96
#define NKS    576        // NPIX/16 key 16-slices per batch
#define QBLKS  288        // NPIX/32 query blocks (32 queries per block)
#define KPART  4          // key partitions, one per wave in a block
#define KEYS_P 2304       // NPIX/KPART
#define NCHUNK 36         // 64 keys per chunk
#define SM_F   2080       // per-slot combine floats: 2048 O + 32 L (4 slots)
#define NP4    2304       // NPIX/4
#define KSTEP2 1024       // kp elements per 64-key chunk (64*16)
#define VSTEP  4096       // vswz elements per chunk (4 kslices x 2 ctiles x 512)

typedef short bf16x8 __attribute__((ext_vector_type(8)));
typedef float f32x4  __attribute__((ext_vector_type(4)));
typedef float f32x16 __attribute__((ext_vector_type(16)));
typedef unsigned u32x4 __attribute__((ext_vector_type(4)));
typedef unsigned uint2v __attribute__((ext_vector_type(2)));

// single-instruction packed f32->bf16 (RNE), a -> low16, b -> high16
static __device__ __forceinline__ unsigned pack2bf(float a, float b){
    unsigned r;
    asm("v_cvt_pk_bf16_f32 %0, %1, %2" : "=v"(r) : "v"(a), "v"(b));
    return r;
}

// raw v_exp_f32 (2^x). Inputs here are bounded QK scores — no denormal fixup needed.
static __device__ __forceinline__ float exp2r(float x){
    return __builtin_amdgcn_exp2f(x);
}

// ---------- fused prep, 8-channel register blocking (unchanged from r5) ----------
__global__ __launch_bounds__(256) void prep_kernel(
    const float* __restrict__ x,
    const float* __restrict__ wq, const float* __restrict__ bq,
    const float* __restrict__ wk, const float* __restrict__ bk,
    const float* __restrict__ wv, const float* __restrict__ bv,
    __hip_bfloat16* __restrict__ qp, __hip_bfloat16* __restrict__ kp,
    __hip_bfloat16* __restrict__ vswz, float* __restrict__ amean)
{
    const int blk = blockIdx.x, tid = threadIdx.x;
    if (blk < 144){
        int t  = blk*256 + tid;            // (b, c8, n4)
        int n  = (t % NP4) * 4;
        int c8 = (t / NP4) & 7;            // wave-uniform (NP4 % 64 == 0)
        int b  = t / (NP4*8);
        c8 = __builtin_amdgcn_readfirstlane(c8);
        b  = __builtin_amdgcn_readfirstlane(b);
        float acc[8][4];
#pragma unroll
        for (int k = 0; k < 8; ++k){
            float bvv = bv[c8*8 + k];
            acc[k][0] = bvv; acc[k][1] = bvv; acc[k][2] = bvv; acc[k][3] = bvv;
        }
#pragma unroll 4
        for (int ci = 0; ci < C_CH; ++ci){
            const float4 xv = *reinterpret_cast<const float4*>(
                x + (size_t)(b*C_CH + ci)*NPIX + n);
#pragma unroll
            for (int k = 0; k < 8; ++k){
                float w = wv[(c8*8 + k)*C_CH + ci];
                acc[k][0] = fmaf(xv.x, w, acc[k][0]);
                acc[k][1] = fmaf(xv.y, w, acc[k][1]);
                acc[k][2] = fmaf(xv.z, w, acc[k][2]);
                acc[k][3] = fmaf(xv.w, w, acc[k][3]);
            }
        }
#pragma unroll
        for (int k = 0; k < 8; ++k){
            int c = c8*8 + k;
            size_t base = ((size_t)((b*NKS + (n >> 4))*2 + (c >> 5)))*512
                        + (((n >> 3) & 1) << 8) + ((c & 31) << 3) + (n & 7);
            unsigned long long wpk =
                (unsigned long long)pack2bf(acc[k][0], acc[k][1]) |
                ((unsigned long long)pack2bf(acc[k][2], acc[k][3]) << 32);
            *reinterpret_cast<unsigned long long*>(vswz + base) = wpk;
        }
    } else if (blk < 180){
        int t  = (blk - 144)*256 + tid;    // (b, o8, n4)
        int n  = (t % NP4) * 4;
        int o8 = (t / NP4) & 1;            // wave-uniform; 0 => q, 1 => k
        int b  = t / (NP4*2);
        o8 = __builtin_amdgcn_readfirstlane(o8);
        b  = __builtin_amdgcn_readfirstlane(b);
        const bool isq = (o8 == 0);
        const float* w    = isq ? wq : wk;
        const float* bias = isq ? bq : bk;
        float acc[8][4];
#pragma unroll
        for (int k = 0; k < 8; ++k){
            float bb = bias[k];
            acc[k][0] = bb; acc[k][1] = bb; acc[k][2] = bb; acc[k][3] = bb;
        }
#pragma unroll 4
        for (int ci = 0; ci < C_CH; ++ci){
            const float4 xv = *reinterpret_cast<const float4*>(
                x + (size_t)(b*C_CH + ci)*NPIX + n);
#pragma unroll
            for (int k = 0; k < 8; ++k){
                float wv_ = w[k*C_CH + ci];
                acc[k][0] = fmaf(xv.x, wv_, acc[k][0]);
                acc[k][1] = fmaf(xv.y, wv_, acc[k][1]);
                acc[k][2] = fmaf(xv.z, wv_, acc[k][2]);
                acc[k][3] = fmaf(xv.w, wv_, acc[k][3]);
            }
        }
        if (isq){  // fold log2(e) so softmax uses native exp2
#pragma unroll
            for (int k = 0; k < 8; ++k)
#pragma unroll
                for (int px = 0; px < 4; ++px) acc[k][px] *= 1.44269504f;
        }
        __hip_bfloat16* dst = isq ? qp : kp;
        u32x4 zr; zr[0] = 0; zr[1] = 0; zr[2] = 0; zr[3] = 0;
#pragma unroll
        for (int px = 0; px < 4; ++px){
            u32x4 row;
            row[0] = pack2bf(acc[0][px], acc[1][px]);
            row[1] = pack2bf(acc[2][px], acc[3][px]);
            row[2] = pack2bf(acc[4][px], acc[5][px]);
            row[3] = pack2bf(acc[6][px], acc[7][px]);
            __hip_bfloat16* d0 = dst + ((size_t)(b*NPIX + n + px))*QKS;
            *reinterpret_cast<u32x4*>(d0)     = row;
            *reinterpret_cast<u32x4*>(d0 + 8) = zr;   // zero pad dims 8..15
        }
    } else {
        int bc = blk - 180;                // (b*64+c)
        float s = 0.f;
        for (int i = tid; i < NPIX; i += 256) s += x[(size_t)bc*NPIX + i];
#pragma unroll
        for (int o = 32; o > 0; o >>= 1) s += __shfl_down(s, o, 64);
        __shared__ float red[4];
        if ((tid & 63) == 0) red[tid >> 6] = s;
        __syncthreads();
        if (tid == 0) amean[bc] = (red[0] + red[1] + red[2] + red[3]) * (1.f / (float)NPIX);
    }
}

// ---------- fused attention: 32x32x16 MFMA, 4 waves/block, full grid co-resident ----------
__global__ __launch_bounds__(256, 4) void flash_fused(
    const __hip_bfloat16* __restrict__ qp,
    const __hip_bfloat16* __restrict__ kp,
    const __hip_bfloat16* __restrict__ vswz,
    const float* __restrict__ amean,
    const float* __restrict__ sw1, const float* __restrict__ sb1,
    const float* __restrict__ s1w, const float* __restrict__ s1b,
    const float* __restrict__ s1m, const float* __restrict__ s1v,
    const float* __restrict__ sw2, const float* __restrict__ sb2,
    const float* __restrict__ s2w, const float* __restrict__ s2b,
    const float* __restrict__ s2m, const float* __restrict__ s2v,
    const float* __restrict__ x,
    const float* __restrict__ gamma,
    const float* __restrict__ bnw, const float* __restrict__ bnb,
    const float* __restrict__ bnm, const float* __restrict__ bnv,
    float* __restrict__ out)
{
    __shared__ __align__(16) float sm[4*SM_F];   // 33280 B: 4 combine slots

    const int qt2 = blockIdx.x, b = blockIdx.y;   // 32 queries per block
    const int p  = threadIdx.x >> 6;     // wave = key partition (0..3)
    const int l  = threadIdx.x & 63;
    const int lc = l & 31;               // column lane (query / channel)
    const int lh = l >> 5;               // lane half (k-elem group)

    // Q fragment: B-operand, B[k=(lh*8+e)][col=query lc]; pad dims read zeros
    bf16x8 qfrag = *reinterpret_cast<const bf16x8*>(
        qp + ((size_t)(b*NPIX + qt2*32 + lc))*QKS + lh*8);

    bf16x8 ones;          // bf16 1.0 x8 — A-frag for the L-denominator MFMA
#pragma unroll
    for (int i = 0; i < 8; ++i) ones[i] = (short)0x3F80;

    f32x16 zero16;
#pragma unroll
    for (int i = 0; i < 16; ++i) zero16[i] = 0.f;

    f32x16 Of0 = zero16, Of1 = zero16;   // O^T accum: [channel row][query col], 2 ctiles
    f32x16 Lacc = zero16;                // L accum (all rows identical)

    // running pointers
    const __hip_bfloat16* kptr = kp + ((size_t)(b*NPIX + p*KEYS_P + lc))*QKS + lh*8;
    const __hip_bfloat16* vptr = vswz + ((size_t)((b*NKS + p*(KEYS_P/16))*2))*512 + l*8;

    auto CHUNK = [&](const bf16x8& k0, const bf16x8& k1){
        // V tiles for this chunk (issued first; consumed after QK+exp2 — self-hiding)
        bf16x8 vf[8];
#pragma unroll
        for (int t = 0; t < 8; ++t)
            vf[t] = *reinterpret_cast<const bf16x8*>(vptr + t*512);
        vptr += VSTEP;

        // QK^T per 32-key tile; P = exp2(S) via raw v_exp_f32; cvt_pk row pairs
        unsigned D[16];
#pragma unroll
        for (int kt = 0; kt < 2; ++kt){
            f32x16 s = __builtin_amdgcn_mfma_f32_32x32x16_bf16(
                kt ? k1 : k0, qfrag, zero16, 0, 0, 0);
#pragma unroll
            for (int g = 0; g < 4; ++g){
                float e0 = exp2r(s[4*g+0]), e1 = exp2r(s[4*g+1]);
                float e2 = exp2r(s[4*g+2]), e3 = exp2r(s[4*g+3]);
                D[kt*8 + g*2 + 0] = pack2bf(e0, e1);
                D[kt*8 + g*2 + 1] = pack2bf(e2, e3);
            }
        }
        // per 16-key slice: build PV B-frag with 2 permlane32_swaps, then MFMA
#pragma unroll
        for (int ks = 0; ks < 4; ++ks){
            const int base = (ks >> 1)*8 + (ks & 1)*4;
            uint2v r0 = __builtin_amdgcn_permlane32_swap(D[base+0], D[base+2], false, false);
            uint2v r1 = __builtin_amdgcn_permlane32_swap(D[base+1], D[base+3], false, false);
            u32x4 pu; pu[0] = r0[0]; pu[1] = r1[0]; pu[2] = r0[1]; pu[3] = r1[1];
            bf16x8 pf = __builtin_bit_cast(bf16x8, pu);
            Of0  = __builtin_amdgcn_mfma_f32_32x32x16_bf16(vf[ks*2+0], pf, Of0, 0, 0, 0);
            Of1  = __builtin_amdgcn_mfma_f32_32x32x16_bf16(vf[ks*2+1], pf, Of1, 0, 0, 0);
            Lacc = __builtin_amdgcn_mfma_f32_32x32x16_bf16(ones,       pf, Lacc, 0, 0, 0);
        }
    };

    // K ping-pong: prologue chunk 0
    bf16x8 kA0 = *reinterpret_cast<const bf16x8*>(kptr);
    bf16x8 kA1 = *reinterpret_cast<const bf16x8*>(kptr + 512);
    kptr += KSTEP2;
    bf16x8 kB0, kB1;
    for (int it = 0; it < (NCHUNK - 2)/2; ++it){
        kB0 = *reinterpret_cast<const bf16x8*>(kptr);
        kB1 = *reinterpret_cast<const bf16x8*>(kptr + 512);
        kptr += KSTEP2;
        CHUNK(kA0, kA1);
        kA0 = *reinterpret_cast<const bf16x8*>(kptr);
        kA1 = *reinterpret_cast<const bf16x8*>(kptr + 512);
        kptr += KSTEP2;
        CHUNK(kB0, kB1);
    }
    kB0 = *reinterpret_cast<const bf16x8*>(kptr);
    kB1 = *reinterpret_cast<const bf16x8*>(kptr + 512);
    CHUNK(kA0, kA1);
    CHUNK(kB0, kB1);

    // --- SE a1 (after hot loop; only needs amean) ---
    float a1r;
    {
        int r8 = l & 7;
        float s = sb1[r8];
#pragma unroll 8
        for (int c = 0; c < C_CH; ++c)
            s = fmaf(amean[b*C_CH + c], sw1[r8*C_CH + c], s);
        s = (s - s1m[r8]) * (s1w[r8] * rsqrtf(s1v[r8] + 1e-5f)) + s1b[r8];
        a1r = fmaxf(s, 0.f);
    }

    // --- each wave writes its own slot; one barrier; combine 4 slots ---
#pragma unroll
    for (int r = 0; r < 16; ++r){
        sm[p*SM_F +        r*64 + l] = Of0[r];
        sm[p*SM_F + 1024 + r*64 + l] = Of1[r];
    }
    if (l < 32) sm[p*SM_F + 2048 + l] = Lacc[0];
    __syncthreads();

    // --- combine + SE a2 + epilogue: out = x*(1+a2) + BN(gamma*O/L) ---
    {
        const int i   = lc;                // query
        const int cgs = p*2 + lh;          // channel group (0..7), 8 channels each
        float gam = gamma[0];

        // SE a2 for this thread's 8 channels (gather a1 via shuffles)
        float a1g[8];
#pragma unroll
        for (int j = 0; j < 8; ++j) a1g[j] = __shfl(a1r, (l & 56) | j, 64);

        float L = 0.f;
#pragma unroll
        for (int q = 0; q < 4; ++q) L += sm[q*SM_F + 2048 + i];
        float invL = 1.f / L;
        int n = qt2*32 + i;
#pragma unroll
        for (int r = 0; r < 8; ++r){
            int c = cgs*8 + r;
            float s = sb2[c];
#pragma unroll
            for (int j = 0; j < 8; ++j) s = fmaf(a1g[j], sw2[c*NQ + j], s);
            s = (s - s2m[c]) * (s2w[c] * rsqrtf(s2v[c] + 1e-5f)) + s2b[c];
            float a2v = fmaxf(s, 0.f);

            // channel -> (ctile, reg, lane-half) in the 32x32 C layout
            int c5   = c & 31;
            int reg  = (c5 & 3) + 4*(c5 >> 3);
            int lsrc = (c5 >> 2) & 1;
            int o    = (c >> 5)*1024 + reg*64 + lsrc*32 + i;
            float O = 0.f;
#pragma unroll
            for (int q = 0; q < 4; ++q) O += sm[q*SM_F + o];
            float pam = gam * O * invL;
            pam = (pam - bnm[c]) * (bnw[c] * rsqrtf(bnv[c] + 1e-5f)) + bnb[c];
            float xv = x[(size_t)(b*C_CH + c)*NPIX + n];
            out[(size_t)(b*C_CH + c)*NPIX + n] = fmaf(xv, a2v, xv + pam);
        }
    }
}

extern "C" void kernel_launch(void* const* d_in, const int* in_sizes, int n_in,
                              void* d_out, int out_size, void* d_ws, size_t ws_size,
                              hipStream_t stream)
{
    const float* x     = (const float*)d_in[0];
    const float* wq    = (const float*)d_in[1];
    const float* bq    = (const float*)d_in[2];
    const float* wk    = (const float*)d_in[3];
    const float* bk    = (const float*)d_in[4];
    const float* wv    = (const float*)d_in[5];
    const float* bv    = (const float*)d_in[6];
    const float* gamma = (const float*)d_in[7];
    const float* bnw   = (const float*)d_in[8];
    const float* bnb   = (const float*)d_in[9];
    const float* bnm   = (const float*)d_in[10];
    const float* bnv   = (const float*)d_in[11];
    const float* sw1   = (const float*)d_in[12];
    const float* sb1   = (const float*)d_in[13];
    const float* s1w   = (const float*)d_in[14];
    const float* s1b   = (const float*)d_in[15];
    const float* s1m   = (const float*)d_in[16];
    const float* s1v   = (const float*)d_in[17];
    const float* sw2   = (const float*)d_in[18];
    const float* sb2   = (const float*)d_in[19];
    const float* s2w   = (const float*)d_in[20];
    const float* s2b   = (const float*)d_in[21];
    const float* s2m   = (const float*)d_in[22];
    const float* s2v   = (const float*)d_in[23];

    size_t off = 0;
    auto give = [&](size_t bytes) -> void* {
        void* r = (char*)d_ws + off;
        off += (bytes + 255) & ~(size_t)255;
        return r;
    };
    __hip_bfloat16* qp   = (__hip_bfloat16*)give((size_t)B_SZ*NPIX*QKS*2);
    __hip_bfloat16* kp   = (__hip_bfloat16*)give((size_t)B_SZ*NPIX*QKS*2);
    __hip_bfloat16* vswz = (__hip_bfloat16*)give((size_t)B_SZ*C_CH*NPIX*2);
    float* amean = (float*)give((size_t)B_SZ*C_CH*4);

    prep_kernel<<<dim3(308), dim3(256), 0, stream>>>(x, wq, bq, wk, bk, wv, bv,
                                                     qp, kp, vswz, amean);
    flash_fused<<<dim3(QBLKS, B_SZ), dim3(256), 0, stream>>>(
        qp, kp, vswz, amean,
        sw1, sb1, s1w, s1b, s1m, s1v,
        sw2, sb2, s2w, s2b, s2m, s2v,
        x, gamma, bnw, bnb, bnm, bnv, (float*)d_out);
}